// Round 9
// baseline (780.642 us; speedup 1.0000x reference)
//
#include <hip/hip_runtime.h>

typedef _Float16 f16;
typedef f16 f16x8 __attribute__((ext_vector_type(8)));
typedef float f32x4 __attribute__((ext_vector_type(4)));

static constexpr int NDATA = 50000;
static constexpr int DF    = 3072;
static constexpr int BP    = 256;
static constexpr int NGRPQ = 792;     // 64-row softmax groups (792*64 = 50688)
static constexpr int NW    = 50688;   // W row stride / padded N

// workspace offsets (bytes)
static constexpr size_t OFF_W  = 0;            // W : 256*50688*2 = 25952256
static constexpr size_t OFF_XH = 25952256;     // xh: 1572864
static constexpr size_t OFF_MP = 27525120;     // Mp: 792*256*4 = 811008
static constexpr size_t OFF_LP = 28336128;     // Lp: 811008
static constexpr size_t OFF_M  = 29147136;     // M : 1024
static constexpr size_t OFF_L  = 29148160;     // L : 1024
static constexpr size_t OFF_P  = 29149184;     // P : nch * 3145728
static constexpr size_t SLAB   = (size_t)BP * DF * 4;

// lgkm-only barrier: LDS ordered, global loads stay IN FLIGHT (no vmcnt drain)
__device__ __forceinline__ void barrier_lgkm() {
  __builtin_amdgcn_sched_barrier(0);
  asm volatile("s_waitcnt lgkmcnt(0)" ::: "memory");
  __builtin_amdgcn_s_barrier();
  __builtin_amdgcn_sched_barrier(0);
}

// ---------------- K1: x -> fp16 ----------------
__global__ void k_prep_x(const float* __restrict__ x, f16* __restrict__ xh) {
  int i = blockIdx.x * 256 + threadIdx.x;
  f32x4 v = ((const f32x4*)x)[i];
  union { f16 f[4]; short4 s; } u;
  u.f[0] = (f16)v[0]; u.f[1] = (f16)v[1]; u.f[2] = (f16)v[2]; u.f[3] = (f16)v[3];
  ((short4*)xh)[i] = u.s;
}

// ---------------- K2: S-tile via MFMA -> per-group softmax partials + W' ----------------
// 256 thr (4 waves), tile 64n x 256b; wave = 64n x 64b (wave-private cols).
// A (data) through tiny LDS (8KB/step); B (xh, L2-resident) DIRECT per-wave with
// 1-step register prefetch. A 2-deep. One lgkm barrier per K-step.
__global__ __launch_bounds__(256) void k_qk(const float* __restrict__ data,
                                            const f16* __restrict__ xh,
                                            const float* __restrict__ sigma,
                                            f16* __restrict__ W,
                                            float* __restrict__ Mp,
                                            float* __restrict__ Lp) {
  __shared__ char smem[37120];
  f16* As    = (f16*)smem;                 // loop: 2 x [64][40] f16 = 10240 B
  f16* trans = (f16*)smem;                 // epilogue alias: [256][72] = 36864 B
  float* dn_s = (float*)(smem + 36864);    // [64]

  const int tid = threadIdx.x;
  const int wid = tid >> 6, lane = tid & 63;
  const int l15 = lane & 15, kg = lane >> 4;
  const int n0 = blockIdx.x * 64;

  // A staging: row = tid>>2 (64 rows), 8 floats at (tid&3)*8
  const int arow = tid >> 2, ak = (tid & 3) * 8;
  const int agr = n0 + arow;
  const float* ap = data + (size_t)(agr < NDATA ? agr : NDATA - 1) * DF + ak;

  // B direct: wave-private cols wid*64 + c*16 + l15, k-slice kg*8
  const f16* bp0 = xh + (size_t)(wid * 64 +  0 + l15) * DF + kg * 8;
  const f16* bp1 = xh + (size_t)(wid * 64 + 16 + l15) * DF + kg * 8;
  const f16* bp2 = xh + (size_t)(wid * 64 + 32 + l15) * DF + kg * 8;
  const f16* bp3 = xh + (size_t)(wid * 64 + 48 + l15) * DF + kg * 8;

  f32x4 acc[4][4] = {};
  float sq = 0.f;
  f32x4 aA0, aA1, aB0, aB1;
  f16x8 Bc0, Bc1, Bc2, Bc3, Bn0, Bn1, Bn2, Bn3;

  auto gloadA = [&](int k0, f32x4& a0, f32x4& a1) {
    a0 = *(const f32x4*)(ap + k0);
    a1 = *(const f32x4*)(ap + k0 + 4);
  };
  auto gloadB = [&](int k0, f16x8& b0, f16x8& b1, f16x8& b2, f16x8& b3) {
    b0 = *(const f16x8*)(bp0 + k0);
    b1 = *(const f16x8*)(bp1 + k0);
    b2 = *(const f16x8*)(bp2 + k0);
    b3 = *(const f16x8*)(bp3 + k0);
  };
  auto swriteA = [&](int buf, f32x4& a0, f32x4& a1) {
    f16x8 h;
#pragma unroll
    for (int j = 0; j < 4; ++j) {
      h[j] = (f16)a0[j];     sq = fmaf(a0[j], a0[j], sq);
      h[4 + j] = (f16)a1[j]; sq = fmaf(a1[j], a1[j], sq);
    }
    *(f16x8*)(As + buf * 2560 + arow * 40 + ak) = h;
  };
  auto compute = [&](int buf, f16x8& b0, f16x8& b1, f16x8& b2, f16x8& b3) {
#pragma unroll
    for (int q = 0; q < 4; ++q) {
      f16x8 af = *(const f16x8*)(As + buf * 2560 + (q * 16 + l15) * 40 + kg * 8);
      acc[q][0] = __builtin_amdgcn_mfma_f32_16x16x32_f16(af, b0, acc[q][0], 0, 0, 0);
      acc[q][1] = __builtin_amdgcn_mfma_f32_16x16x32_f16(af, b1, acc[q][1], 0, 0, 0);
      acc[q][2] = __builtin_amdgcn_mfma_f32_16x16x32_f16(af, b2, acc[q][2], 0, 0, 0);
      acc[q][3] = __builtin_amdgcn_mfma_f32_16x16x32_f16(af, b3, acc[q][3], 0, 0, 0);
    }
  };

  gloadA(0, aA0, aA1);
  swriteA(0, aA0, aA1);
  gloadA(32, aB0, aB1);
  gloadB(0, Bc0, Bc1, Bc2, Bc3);
  barrier_lgkm();

  for (int ks = 0; ks < 96; ks += 2) {
    if (ks + 2 < 96) gloadA((ks + 2) * 32, aA0, aA1);
    gloadB((ks + 1) * 32, Bn0, Bn1, Bn2, Bn3);
    compute(0, Bc0, Bc1, Bc2, Bc3);
    swriteA(1, aB0, aB1);
    barrier_lgkm();
    if (ks + 3 < 96) gloadA((ks + 3) * 32, aB0, aB1);
    if (ks + 2 < 96) gloadB((ks + 2) * 32, Bc0, Bc1, Bc2, Bc3);
    compute(1, Bn0, Bn1, Bn2, Bn3);
    if (ks + 2 < 96) swriteA(0, aA0, aA1);
    barrier_lgkm();
  }

  // |d|^2: reduce across the 4 staging threads of each row
  sq += __shfl_xor(sq, 1);
  sq += __shfl_xor(sq, 2);
  if ((tid & 3) == 0) dn_s[arow] = sq;
  __syncthreads();

  const float sg  = sigma[0];
  const float inv = 0.5f / (sg * sg);
  float dn[4][4];
  bool ok[4][4];
#pragma unroll
  for (int q = 0; q < 4; ++q)
#pragma unroll
    for (int r = 0; r < 4; ++r) {
      const int rl = q * 16 + kg * 4 + r;    // C/D: row=(l>>4)*4+reg, per q-subtile
      dn[q][r] = dn_s[rl];
      ok[q][r] = (n0 + rl) < NDATA;
    }

  // pass 1: column max over all 64 rows (cols wave-private -> shfl over kg only)
  float pm[4];
#pragma unroll
  for (int c = 0; c < 4; ++c) pm[c] = -1e30f;
#pragma unroll
  for (int q = 0; q < 4; ++q)
#pragma unroll
    for (int r = 0; r < 4; ++r)
#pragma unroll
      for (int c = 0; c < 4; ++c) {
        float v = ok[q][r] ? (2.f * acc[q][c][r] - dn[q][r]) * inv : -1e30f;
        pm[c] = fmaxf(pm[c], v);
      }
#pragma unroll
  for (int c = 0; c < 4; ++c) {
    pm[c] = fmaxf(pm[c], __shfl_xor(pm[c], 16));
    pm[c] = fmaxf(pm[c], __shfl_xor(pm[c], 32));
  }

  // pass 2: w = exp(v - m), accumulate l, transposed store
  float pl[4] = {};
#pragma unroll
  for (int q = 0; q < 4; ++q)
#pragma unroll
    for (int r = 0; r < 4; ++r) {
      const int rl = q * 16 + kg * 4 + r;
#pragma unroll
      for (int c = 0; c < 4; ++c) {
        float v = (2.f * acc[q][c][r] - dn[q][r]) * inv;
        float w = ok[q][r] ? __expf(v - pm[c]) : 0.f;
        pl[c] += w;
        trans[(wid * 64 + c * 16 + l15) * 72 + rl] = (f16)w;
      }
    }
#pragma unroll
  for (int c = 0; c < 4; ++c) {
    pl[c] += __shfl_xor(pl[c], 16);
    pl[c] += __shfl_xor(pl[c], 32);
  }
  if (kg == 0) {
#pragma unroll
    for (int c = 0; c < 4; ++c) {
      const int col = wid * 64 + c * 16 + l15;
      Mp[blockIdx.x * 256 + col] = pm[c];
      Lp[blockIdx.x * 256 + col] = pl[c];
    }
  }
  __syncthreads();
  // transpose readout -> W' (64 contiguous f16 per column; FIXED: full 64, j<8)
  {
    const int col = tid;
    const f16* src = trans + col * 72;
    f16* dst = W + (size_t)col * NW + n0;
#pragma unroll
    for (int j = 0; j < 8; ++j)
      *(f16x8*)(dst + j * 8) = *(const f16x8*)(src + j * 8);
  }
}

// ---------------- K3: combine partials -> M[b], L[b] ----------------
__global__ void k_comb(const float* __restrict__ Mp, const float* __restrict__ Lp,
                       float* __restrict__ M, float* __restrict__ L, int ngrp) {
  __shared__ float ms[4][256], ls[4][256];
  const int tid = threadIdx.x;
  const int q = tid >> 8, b = tid & 255;
  float m = -1e38f, l = 0.f;
  for (int g = q; g < ngrp; g += 4) {
    float m2 = Mp[g * 256 + b], l2 = Lp[g * 256 + b];
    if (m2 > m) { l = l * __expf(m - m2) + l2; m = m2; }
    else        { l += l2 * __expf(m2 - m); }
  }
  ms[q][b] = m; ls[q][b] = l;
  __syncthreads();
  if (q == 0) {
#pragma unroll
    for (int j = 1; j < 4; ++j) {
      float m2 = ms[j][b], l2 = ls[j][b];
      if (m2 > m) { l = l * __expf(m - m2) + l2; m = m2; }
      else        { l += l2 * __expf(m2 - m); }
    }
    M[b] = m; L[b] = l;
  }
}

// ---------------- K4: eps partials = (W*exp(Mp-M)) @ data, split-K over n ----------------
// 256 thr (4 waves), tile 256b x 64d; wave = 64b x 64d (wave-private b rows).
// W direct from L2 (1-deep prefetch, rescale fused); data through LDS (2-deep).
__global__ __launch_bounds__(256) void k_pv(const float* __restrict__ data,
                                            const f16* __restrict__ W,
                                            const float* __restrict__ Mp,
                                            const float* __restrict__ M,
                                            float* __restrict__ part,
                                            int chn, int per8) {
  __shared__ uint32_t T[2][64 * 20];   // [d][n-pair(16)+pad4] packed f16 pairs
  const int tid = threadIdx.x;
  const int wid = tid >> 6, lane = tid & 63;
  const int l15 = lane & 15, kg = lane >> 4;
  const int bid = blockIdx.x;
  const int swz = (bid & 7) * per8 + (bid >> 3);   // XCD-chunked (grid % 8 == 0)
  const int chunk = swz / 48;
  const int dt = swz % 48;
  const int d0 = dt * 64;
  const int nstart = chunk * chn;
  const int kst = chn >> 5;
  const int np = tid >> 4;            // n-pair 0..15
  const int d4 = (tid & 15) * 4;      // d 0..60 step 4

  f32x4 acc[4][4] = {};
  int bq[4];
  float Mb[4];
  const f16* wp[4];
#pragma unroll
  for (int q = 0; q < 4; ++q) {
    bq[q] = wid * 64 + q * 16 + l15;
    Mb[q] = M[bq[q]];
    wp[q] = W + (size_t)bq[q] * NW + nstart + kg * 8;
  }

  f32x4 gaA, gbA, gaB, gbB;
  f16x8 wc0, wc1, wc2, wc3, wn0, wn1, wn2, wn3;
  float mc0, mc1, mc2, mc3, mn0, mn1, mn2, mn3;

  auto gload = [&](int ks, f32x4& ga, f32x4& gb) {
    int n = nstart + ks * 32 + np * 2;
    int na = n < NDATA ? n : NDATA - 1;           // tail rows have W==0
    int nb = (n + 1) < NDATA ? (n + 1) : NDATA - 1;
    ga = *(const f32x4*)(data + (size_t)na * DF + d0 + d4);
    gb = *(const f32x4*)(data + (size_t)nb * DF + d0 + d4);
  };
  auto wload = [&](int ks, f16x8& w0, f16x8& w1, f16x8& w2, f16x8& w3,
                   float& m0, float& m1, float& m2, float& m3) {
    w0 = *(const f16x8*)(wp[0] + ks * 32);
    w1 = *(const f16x8*)(wp[1] + ks * 32);
    w2 = *(const f16x8*)(wp[2] + ks * 32);
    w3 = *(const f16x8*)(wp[3] + ks * 32);
    int gq = (nstart + ks * 32) >> 6;
    m0 = Mp[gq * 256 + bq[0]];
    m1 = Mp[gq * 256 + bq[1]];
    m2 = Mp[gq * 256 + bq[2]];
    m3 = Mp[gq * 256 + bq[3]];
  };
  auto twrite = [&](int buf, f32x4& ga, f32x4& gb) {
#pragma unroll
    for (int j = 0; j < 4; ++j) {
      int d = d4 + j;
      int pn = np ^ (((d >> 3) & 3) << 2);        // pair-unit bank swizzle
      union { f16 f[2]; uint32_t u; } u;
      u.f[0] = (f16)ga[j]; u.f[1] = (f16)gb[j];
      T[buf][d * 20 + pn] = u.u;
    }
  };
  auto compute = [&](int buf, f16x8& w0, f16x8& w1, f16x8& w2, f16x8& w3,
                     float m0, float m1, float m2, float m3) {
    f16 h0 = (f16)__expf(m0 - Mb[0]);
    f16 h1 = (f16)__expf(m1 - Mb[1]);
    f16 h2 = (f16)__expf(m2 - Mb[2]);
    f16 h3 = (f16)__expf(m3 - Mb[3]);
    f16x8 a0, a1, a2, a3;
#pragma unroll
    for (int j = 0; j < 8; ++j) {
      a0[j] = w0[j] * h0; a1[j] = w1[j] * h1;
      a2[j] = w2[j] * h2; a3[j] = w3[j] * h3;
    }
#pragma unroll
    for (int c = 0; c < 4; ++c) {
      int d = c * 16 + l15;
      int dw = d * 20 + ((kg * 4) ^ (((d >> 3) & 3) << 2));
      f16x8 bf = *(const f16x8*)(&T[buf][dw]);
      acc[0][c] = __builtin_amdgcn_mfma_f32_16x16x32_f16(a0, bf, acc[0][c], 0, 0, 0);
      acc[1][c] = __builtin_amdgcn_mfma_f32_16x16x32_f16(a1, bf, acc[1][c], 0, 0, 0);
      acc[2][c] = __builtin_amdgcn_mfma_f32_16x16x32_f16(a2, bf, acc[2][c], 0, 0, 0);
      acc[3][c] = __builtin_amdgcn_mfma_f32_16x16x32_f16(a3, bf, acc[3][c], 0, 0, 0);
    }
  };

  gload(0, gaA, gbA);
  wload(0, wc0, wc1, wc2, wc3, mc0, mc1, mc2, mc3);
  twrite(0, gaA, gbA);
  gload(1, gaB, gbB);
  barrier_lgkm();

  for (int ks = 0; ks < kst; ks += 2) {
    if (ks + 2 < kst) gload(ks + 2, gaA, gbA);
    if (ks + 1 < kst) wload(ks + 1, wn0, wn1, wn2, wn3, mn0, mn1, mn2, mn3);
    compute(0, wc0, wc1, wc2, wc3, mc0, mc1, mc2, mc3);
    if (ks + 1 < kst) twrite(1, gaB, gbB);
    barrier_lgkm();
    if (ks + 1 < kst) {
      if (ks + 3 < kst) gload(ks + 3, gaB, gbB);
      if (ks + 2 < kst) wload(ks + 2, wc0, wc1, wc2, wc3, mc0, mc1, mc2, mc3);
      compute(1, wn0, wn1, wn2, wn3, mn0, mn1, mn2, mn3);
      if (ks + 2 < kst) twrite(0, gaA, gbA);
      barrier_lgkm();
    }
  }

  float* pp = part + (size_t)chunk * (BP * DF);
#pragma unroll
  for (int q = 0; q < 4; ++q)
#pragma unroll
    for (int c = 0; c < 4; ++c)
#pragma unroll
      for (int r = 0; r < 4; ++r) {
        int b = wid * 64 + q * 16 + kg * 4 + r;
        int d = d0 + c * 16 + l15;
        pp[(size_t)b * DF + d] = acc[q][c][r];
      }
}

// ---------------- K5: out = (x - (sum partials)/L) / sigma ----------------
__global__ void k_final(const float* __restrict__ x, const float* __restrict__ sigma,
                        const float* __restrict__ part, const float* __restrict__ L,
                        float* __restrict__ out, int nch) {
  int i = blockIdx.x * 256 + threadIdx.x;
  int b = (i * 4) / DF;
  f32x4 s = {};
  for (int c = 0; c < nch; ++c) s += ((const f32x4*)(part + (size_t)c * BP * DF))[i];
  f32x4 xv = ((const f32x4*)x)[i];
  float invL = 1.f / L[b];
  float invsg = 1.f / sigma[0];
  f32x4 r;
#pragma unroll
  for (int j = 0; j < 4; ++j) r[j] = (xv[j] - s[j] * invL) * invsg;
  ((f32x4*)out)[i] = r;
}

extern "C" void kernel_launch(void* const* d_in, const int* in_sizes, int n_in,
                              void* d_out, int out_size, void* d_ws, size_t ws_size,
                              hipStream_t stream) {
  const float* x     = (const float*)d_in[0];
  const float* sigma = (const float*)d_in[1];
  const float* data  = (const float*)d_in[2];
  float* out = (float*)d_out;
  char* ws = (char*)d_ws;

  f16*   W  = (f16*)(ws + OFF_W);
  f16*   xh = (f16*)(ws + OFF_XH);
  float* Mp = (float*)(ws + OFF_MP);
  float* Lp = (float*)(ws + OFF_LP);
  float* M  = (float*)(ws + OFF_M);
  float* L  = (float*)(ws + OFF_L);
  float* P  = (float*)(ws + OFF_P);

  int nch = 16, chn = 3168;                 // grid 768 = exactly 3 blocks/CU
  if (ws_size < OFF_P + 16 * SLAB) { nch = 8; chn = 6336; }
  const int grid_pv = 48 * nch;
  const int per8 = grid_pv / 8;

  k_prep_x<<<768, 256, 0, stream>>>(x, xh);
  k_qk<<<NGRPQ, 256, 0, stream>>>(data, xh, sigma, W, Mp, Lp);
  k_comb<<<1, 1024, 0, stream>>>(Mp, Lp, M, L, NGRPQ);
  k_pv<<<grid_pv, 256, 0, stream>>>(data, W, Mp, M, P, chn, per8);
  k_final<<<768, 256, 0, stream>>>(x, sigma, P, L, out, nch);
}

// Round 11
// 568.786 us; speedup vs baseline: 1.3725x; 1.3725x over previous
//
#include <hip/hip_runtime.h>

typedef _Float16 f16;
typedef f16 f16x8 __attribute__((ext_vector_type(8)));
typedef float f32x4 __attribute__((ext_vector_type(4)));

static constexpr int NDATA = 50000;
static constexpr int DF    = 3072;
static constexpr int BP    = 256;
static constexpr int NW    = 50688;   // W row stride / padded N (396*128)
static constexpr int NGRPQ = 396;     // k_qk blocks = softmax groups (128 n each)
static constexpr int NDT2  = 48;      // d-tiles of 64 in k_pv

// workspace offsets (bytes)
static constexpr size_t OFF_W  = 0;            // W : 256*50688*2 = 25952256
static constexpr size_t OFF_XH = 25952256;     // xh: 1572864
static constexpr size_t OFF_MP = 27525120;     // Mp: 396*256*4 = 405504
static constexpr size_t OFF_LP = 27930624;     // Lp: 405504
static constexpr size_t OFF_M  = 28336128;     // M : 1024
static constexpr size_t OFF_L  = 28337152;     // L : 1024
static constexpr size_t OFF_P  = 28338176;     // P : nch * 3145728
static constexpr size_t SLAB   = (size_t)BP * DF * 4;

// lgkm-only barrier: LDS ordered, global loads stay IN FLIGHT (no vmcnt drain)
__device__ __forceinline__ void barrier_lgkm() {
  __builtin_amdgcn_sched_barrier(0);
  asm volatile("s_waitcnt lgkmcnt(0)" ::: "memory");
  __builtin_amdgcn_s_barrier();
  __builtin_amdgcn_sched_barrier(0);
}

// ---------------- K1: x -> fp16 ----------------
__global__ void k_prep_x(const float* __restrict__ x, f16* __restrict__ xh) {
  int i = blockIdx.x * 256 + threadIdx.x;
  f32x4 v = ((const f32x4*)x)[i];
  union { f16 f[4]; short4 s; } u;
  u.f[0] = (f16)v[0]; u.f[1] = (f16)v[1]; u.f[2] = (f16)v[2]; u.f[3] = (f16)v[3];
  ((short4*)xh)[i] = u.s;
}

// ---------------- K2: S-tile via MFMA -> block softmax partials + W' ----------------
// tile 128n x 256b, 8 waves (wave 32n x 128b, acc[2][8]), K-step 32.
// 2-deep A (data HBM) / 1-deep B (xh L2) register prefetch; 1 lgkm-barrier per step.
__global__ __launch_bounds__(512, 4) void k_qk(const float* __restrict__ data,
                                               const f16* __restrict__ xh,
                                               const float* __restrict__ sigma,
                                               f16* __restrict__ W,
                                               float* __restrict__ Mp,
                                               float* __restrict__ Lp) {
  __shared__ char smem[61952];
  f16 (*As)[5120]  = (f16(*)[5120])smem;              // 2 x 10240 B : [128][40]
  f16 (*Bs)[10240] = (f16(*)[10240])(smem + 20480);   // 2 x 20480 B : [256][40]
  float* dn_s = (float*)(smem + 61440);               // [128]
  float* m4   = (float*)smem;                         // alias: [4][256]
  float* l4   = (float*)(smem + 4096);                // alias: [4][256]
  float* m_s  = (float*)(smem + 8192);                // alias: [256]
  f16*  trans = (f16*)(smem + 20480);                 // alias: [256][72]

  const int tid = threadIdx.x;
  const int wid = tid >> 6, lane = tid & 63;
  const int l15 = lane & 15, kg = lane >> 4;
  const int wr = wid >> 1, wb = wid & 1;
  const int n0 = blockIdx.x * 128;

  // A staging: row = tid>>2 (128 rows), 8 floats at (tid&3)*8
  const int arow = tid >> 2, ak = (tid & 3) * 8;
  const int ar_g = n0 + arow;
  const float* ap = data + (size_t)(ar_g < NDATA ? ar_g : NDATA - 1) * DF + ak;
  // B staging: row = tid>>1 (256 rows), 16 f16 at (tid&1)*16
  const int brow = tid >> 1, bk = (tid & 1) * 16;
  const f16* bp = xh + (size_t)brow * DF + bk;

  f32x4 acc[2][8] = {};
  float sq = 0.f;
  f32x4 a0A, a1A, a0B, a1B;     // two A prefetch sets
  f16x8 rb0, rb1;               // one B prefetch set

  auto gloadA = [&](int k0, f32x4& a0, f32x4& a1) {
    a0 = *(const f32x4*)(ap + k0);
    a1 = *(const f32x4*)(ap + k0 + 4);
  };
  auto gloadB = [&](int k0) {
    rb0 = *(const f16x8*)(bp + k0);
    rb1 = *(const f16x8*)(bp + k0 + 8);
  };
  auto swriteA = [&](int buf, f32x4& a0, f32x4& a1) {
    f16x8 h;
#pragma unroll
    for (int j = 0; j < 4; ++j) {
      h[j] = (f16)a0[j];     sq = fmaf(a0[j], a0[j], sq);
      h[4 + j] = (f16)a1[j]; sq = fmaf(a1[j], a1[j], sq);
    }
    *(f16x8*)(&As[buf][arow * 40 + ak]) = h;
  };
  auto swriteB = [&](int buf) {
    *(f16x8*)(&Bs[buf][brow * 40 + bk]) = rb0;
    *(f16x8*)(&Bs[buf][brow * 40 + bk + 8]) = rb1;
  };
  auto compute = [&](int buf) {
    f16x8 af0 = *(const f16x8*)(&As[buf][(wr * 32 + l15) * 40 + kg * 8]);
    f16x8 af1 = *(const f16x8*)(&As[buf][(wr * 32 + 16 + l15) * 40 + kg * 8]);
#pragma unroll
    for (int c = 0; c < 8; ++c) {
      f16x8 bf = *(const f16x8*)(&Bs[buf][(wb * 128 + c * 16 + l15) * 40 + kg * 8]);
      acc[0][c] = __builtin_amdgcn_mfma_f32_16x16x32_f16(af0, bf, acc[0][c], 0, 0, 0);
      acc[1][c] = __builtin_amdgcn_mfma_f32_16x16x32_f16(af1, bf, acc[1][c], 0, 0, 0);
    }
  };

  gloadA(0, a0A, a1A);
  gloadB(0);
  swriteA(0, a0A, a1A);
  swriteB(0);
  gloadA(32, a0B, a1B);
  barrier_lgkm();

  for (int ks = 0; ks < 96; ks += 2) {
    // step ks (buf 0)
    if (ks + 2 < 96) gloadA((ks + 2) * 32, a0A, a1A);
    gloadB((ks + 1) * 32);                 // ks+1 <= 95 always
    compute(0);
    swriteA(1, a0B, a1B);                  // step ks+1 data
    swriteB(1);
    barrier_lgkm();
    // step ks+1 (buf 1)
    if (ks + 3 < 96) { gloadA((ks + 3) * 32, a0B, a1B); }
    if (ks + 2 < 96) { gloadB((ks + 2) * 32); }
    compute(1);
    if (ks + 2 < 96) { swriteA(0, a0A, a1A); swriteB(0); }
    barrier_lgkm();
  }

  // |d|^2: reduce over 4 k-quarter threads of each row
  sq += __shfl_xor(sq, 1);
  sq += __shfl_xor(sq, 2);
  if ((lane & 3) == 0) dn_s[arow] = sq;
  __syncthreads();

  const float sg  = sigma[0];
  const float inv = 0.5f / (sg * sg);
  float dn[2][4];
  bool ok[2][4];
#pragma unroll
  for (int i = 0; i < 2; ++i)
#pragma unroll
    for (int r = 0; r < 4; ++r) {
      int rl = wr * 32 + i * 16 + kg * 4 + r;
      dn[i][r] = dn_s[rl];
      ok[i][r] = (n0 + rl) < NDATA;
    }

  // pass 1: block-local column max
  float pm[8];
#pragma unroll
  for (int c = 0; c < 8; ++c) pm[c] = -1e30f;
#pragma unroll
  for (int i = 0; i < 2; ++i)
#pragma unroll
    for (int r = 0; r < 4; ++r)
#pragma unroll
      for (int c = 0; c < 8; ++c) {
        float v = ok[i][r] ? (2.f * acc[i][c][r] - dn[i][r]) * inv : -1e30f;
        pm[c] = fmaxf(pm[c], v);
      }
#pragma unroll
  for (int c = 0; c < 8; ++c) {
    pm[c] = fmaxf(pm[c], __shfl_xor(pm[c], 16));
    pm[c] = fmaxf(pm[c], __shfl_xor(pm[c], 32));
  }
  if (kg == 0) {
#pragma unroll
    for (int c = 0; c < 8; ++c) m4[wr * 256 + wb * 128 + c * 16 + l15] = pm[c];
  }
  __syncthreads();
  if (tid < 256)
    m_s[tid] = fmaxf(fmaxf(m4[tid], m4[256 + tid]), fmaxf(m4[512 + tid], m4[768 + tid]));
  __syncthreads();

  float mcol[8];
#pragma unroll
  for (int c = 0; c < 8; ++c) mcol[c] = m_s[wb * 128 + c * 16 + l15];

  // pass 2: two 64-n chunks through the trans buffer
  float pl[8] = {};
#pragma unroll
  for (int h = 0; h < 2; ++h) {
    if ((wr >> 1) == h) {
#pragma unroll
      for (int i = 0; i < 2; ++i)
#pragma unroll
        for (int r = 0; r < 4; ++r) {
          const int rl2 = (wr & 1) * 32 + i * 16 + kg * 4 + r;
#pragma unroll
          for (int c = 0; c < 8; ++c) {
            float v = (2.f * acc[i][c][r] - dn[i][r]) * inv;
            float w = ok[i][r] ? __expf(v - mcol[c]) : 0.f;
            pl[c] += w;
            trans[(wb * 128 + c * 16 + l15) * 72 + rl2] = (f16)w;
          }
        }
    }
    __syncthreads();
    {
      const int col = tid >> 1, q = tid & 1;
      const f16* src = trans + col * 72 + q * 32;
      f16* dst = W + (size_t)col * NW + n0 + h * 64 + q * 32;
#pragma unroll
      for (int j = 0; j < 4; ++j)
        *(f16x8*)(dst + j * 8) = *(const f16x8*)(src + j * 8);
    }
    __syncthreads();
  }

#pragma unroll
  for (int c = 0; c < 8; ++c) {
    pl[c] += __shfl_xor(pl[c], 16);
    pl[c] += __shfl_xor(pl[c], 32);
  }
  if (kg == 0) {
#pragma unroll
    for (int c = 0; c < 8; ++c) l4[wr * 256 + wb * 128 + c * 16 + l15] = pl[c];
  }
  __syncthreads();
  if (tid < 256) {
    Mp[blockIdx.x * 256 + tid] = m_s[tid];
    Lp[blockIdx.x * 256 + tid] = l4[tid] + l4[256 + tid] + l4[512 + tid] + l4[768 + tid];
  }
}

// ---------------- K3: combine partials -> M[b], L[b] ----------------
__global__ void k_comb(const float* __restrict__ Mp, const float* __restrict__ Lp,
                       float* __restrict__ M, float* __restrict__ L, int ngrp) {
  __shared__ float ms[4][256], ls[4][256];
  const int tid = threadIdx.x;
  const int q = tid >> 8, b = tid & 255;
  float m = -1e38f, l = 0.f;
  for (int g = q; g < ngrp; g += 4) {
    float m2 = Mp[g * 256 + b], l2 = Lp[g * 256 + b];
    if (m2 > m) { l = l * __expf(m - m2) + l2; m = m2; }
    else        { l += l2 * __expf(m2 - m); }
  }
  ms[q][b] = m; ls[q][b] = l;
  __syncthreads();
  if (q == 0) {
#pragma unroll
    for (int j = 1; j < 4; ++j) {
      float m2 = ms[j][b], l2 = ls[j][b];
      if (m2 > m) { l = l * __expf(m - m2) + l2; m = m2; }
      else        { l += l2 * __expf(m2 - m); }
    }
    M[b] = m; L[b] = l;
  }
}

// ---------------- K4: eps partials = (W*exp(Mp-M)) @ data, split-K over n ----------------
// 512 thr, tile 256b x 64d, K-step 32. Staging: 4 floats/thread (32n x 64d exact,
// d <= 63, in-bounds — round-10's 8-float variant stomped buf1, racy).
// exp(Mp-M) cached per 128-row Mp group (wave-uniform recompute every 4th step).
__global__ __launch_bounds__(512, 4) void k_pv(const float* __restrict__ data,
                                               const f16* __restrict__ W,
                                               const float* __restrict__ Mp,
                                               const float* __restrict__ M,
                                               float* __restrict__ part,
                                               int chn, int per8) {
  __shared__ f16 T[2][64 * 40];   // [d][n(32)+pad]
  const int tid = threadIdx.x;
  const int wid = tid >> 6, lane = tid & 63;
  const int l15 = lane & 15, kg = lane >> 4;
  const int bid = blockIdx.x;
  const int swz = (bid & 7) * per8 + (bid >> 3);   // XCD-chunked (grid % 8 == 0)
  const int chunk = swz / NDT2;
  const int dt = swz % NDT2;
  const int d0 = dt * 64;
  const int nstart = chunk * chn;
  const int kst = chn >> 5;
  const int nl = tid >> 4, dl = (tid & 15) * 4;    // staging: 32 n-rows x 64 d (exact)

  f32x4 acc[2][4] = {};
  const int b0 = wid * 32 + l15, b1 = b0 + 16;
  const float Mb0 = M[b0], Mb1 = M[b1];
  const f16* wp0 = W + (size_t)b0 * NW + nstart + kg * 8;
  const f16* wp1 = W + (size_t)b1 * NW + nstart + kg * 8;

  f32x4 gA, gB;                 // two data prefetch sets (even / odd steps)
  f16x8 w0c, w1c, w0n, w1n;
  f16 hAc, hBc, hAn, hBn;
  int gqc = -1;
  f16 he0 = (f16)0.f, he1 = (f16)0.f;

  auto gload = [&](int ks, f32x4& g) {
    int row = nstart + ks * 32 + nl;
    int rc = row < NDATA ? row : NDATA - 1;        // tail rows have W==0
    g = *(const f32x4*)(data + (size_t)rc * DF + d0 + dl);
  };
  auto wload = [&](int ks, f16x8& w0, f16x8& w1, f16& ha, f16& hb) {
    w0 = *(const f16x8*)(wp0 + ks * 32);
    w1 = *(const f16x8*)(wp1 + ks * 32);
    int gq = (nstart + ks * 32) >> 7;              // 128-row Mp groups
    if (gq != gqc) {                               // wave-uniform: every 4th step
      gqc = gq;
      he0 = (f16)__expf(Mp[gq * 256 + b0] - Mb0);
      he1 = (f16)__expf(Mp[gq * 256 + b1] - Mb1);
    }
    ha = he0; hb = he1;
  };
  auto twrite = [&](int buf, f32x4& g) {
#pragma unroll
    for (int j = 0; j < 4; ++j) {
      int d = dl + j;                              // d <= 63: in-bounds
      int pn = nl ^ (((d >> 3) & 3) << 3);         // bank swizzle
      T[buf][d * 40 + pn] = (f16)g[j];
    }
  };
  auto compute = [&](int buf, f16x8& w0, f16x8& w1, f16 h0, f16 h1) {
    f16x8 a0, a1;
#pragma unroll
    for (int j = 0; j < 8; ++j) { a0[j] = w0[j] * h0; a1[j] = w1[j] * h1; }
#pragma unroll
    for (int c = 0; c < 4; ++c) {
      int d = c * 16 + l15;
      int pb = (kg * 8) ^ (((d >> 3) & 3) << 3);
      f16x8 bf = *(const f16x8*)(&T[buf][d * 40 + pb]);
      acc[0][c] = __builtin_amdgcn_mfma_f32_16x16x32_f16(a0, bf, acc[0][c], 0, 0, 0);
      acc[1][c] = __builtin_amdgcn_mfma_f32_16x16x32_f16(a1, bf, acc[1][c], 0, 0, 0);
    }
  };

  gload(0, gA);
  wload(0, w0c, w1c, hAc, hBc);
  twrite(0, gA);
  gload(1, gB);
  barrier_lgkm();

  for (int ks = 0; ks < kst; ks += 2) {
    if (ks + 2 < kst) gload(ks + 2, gA);           // data 2 ahead
    if (ks + 1 < kst) wload(ks + 1, w0n, w1n, hAn, hBn);
    compute(0, w0c, w1c, hAc, hBc);
    if (ks + 1 < kst) twrite(1, gB);               // step ks+1 data
    barrier_lgkm();
    if (ks + 1 < kst) {
      if (ks + 3 < kst) gload(ks + 3, gB);
      if (ks + 2 < kst) wload(ks + 2, w0c, w1c, hAc, hBc);
      compute(1, w0n, w1n, hAn, hBn);
      if (ks + 2 < kst) twrite(0, gA);             // step ks+2 data
      barrier_lgkm();
    }
  }

  float* pp = part + (size_t)chunk * (BP * DF);
#pragma unroll
  for (int i = 0; i < 2; ++i)
#pragma unroll
    for (int c = 0; c < 4; ++c)
#pragma unroll
      for (int r = 0; r < 4; ++r) {
        int b = wid * 32 + i * 16 + kg * 4 + r;
        int d = d0 + c * 16 + l15;
        pp[(size_t)b * DF + d] = acc[i][c][r];
      }
}

// ---------------- K5: out = (x - (sum partials)/L) / sigma ----------------
__global__ void k_final(const float* __restrict__ x, const float* __restrict__ sigma,
                        const float* __restrict__ part, const float* __restrict__ L,
                        float* __restrict__ out, int nch) {
  int i = blockIdx.x * 256 + threadIdx.x;
  int b = (i * 4) / DF;
  f32x4 s = {};
  for (int c = 0; c < nch; ++c) s += ((const f32x4*)(part + (size_t)c * BP * DF))[i];
  f32x4 xv = ((const f32x4*)x)[i];
  float invL = 1.f / L[b];
  float invsg = 1.f / sigma[0];
  f32x4 r;
#pragma unroll
  for (int j = 0; j < 4; ++j) r[j] = (xv[j] - s[j] * invL) * invsg;
  ((f32x4*)out)[i] = r;
}

extern "C" void kernel_launch(void* const* d_in, const int* in_sizes, int n_in,
                              void* d_out, int out_size, void* d_ws, size_t ws_size,
                              hipStream_t stream) {
  const float* x     = (const float*)d_in[0];
  const float* sigma = (const float*)d_in[1];
  const float* data  = (const float*)d_in[2];
  float* out = (float*)d_out;
  char* ws = (char*)d_ws;

  f16*   W  = (f16*)(ws + OFF_W);
  f16*   xh = (f16*)(ws + OFF_XH);
  float* Mp = (float*)(ws + OFF_MP);
  float* Lp = (float*)(ws + OFF_LP);
  float* M  = (float*)(ws + OFF_M);
  float* L  = (float*)(ws + OFF_L);
  float* P  = (float*)(ws + OFF_P);

  int nch = 24, chn = 2112;                         // 24*2112 = 50688 exactly
  if (ws_size < OFF_P + 24 * SLAB) { nch = 16; chn = 3168; }
  if (ws_size < OFF_P + 16 * SLAB) { nch = 8;  chn = 6336; }
  const int grid_pv = NDT2 * nch;
  const int per8 = grid_pv / 8;

  k_prep_x<<<768, 256, 0, stream>>>(x, xh);
  k_qk<<<NGRPQ, 512, 0, stream>>>(data, xh, sigma, W, Mp, Lp);
  k_comb<<<1, 1024, 0, stream>>>(Mp, Lp, M, L, NGRPQ);
  k_pv<<<grid_pv, 512, 0, stream>>>(data, W, Mp, M, P, chn, per8);
  k_final<<<768, 256, 0, stream>>>(x, sigma, P, L, out, nch);
}

// Round 12
// 522.753 us; speedup vs baseline: 1.4933x; 1.0881x over previous
//
#include <hip/hip_runtime.h>

typedef _Float16 f16;
typedef f16 f16x8 __attribute__((ext_vector_type(8)));
typedef float f32x4 __attribute__((ext_vector_type(4)));

static constexpr int NDATA = 50000;
static constexpr int DF    = 3072;
static constexpr int BP    = 256;
static constexpr int NW    = 50688;   // W row stride / padded N (396*128)
static constexpr int NGRPQ = 396;     // k_qk blocks = softmax groups (128 n each)
static constexpr int NDT2  = 48;      // d-tiles of 64 in k_pv

// workspace offsets (bytes)
static constexpr size_t OFF_W  = 0;            // W : 256*50688*2 = 25952256
static constexpr size_t OFF_XH = 25952256;     // xh: 1572864
static constexpr size_t OFF_MP = 27525120;     // Mp: 396*256*4 = 405504
static constexpr size_t OFF_LP = 27930624;     // Lp: 405504
static constexpr size_t OFF_M  = 28336128;     // M : 1024
static constexpr size_t OFF_L  = 28337152;     // L : 1024
static constexpr size_t OFF_E  = 28338176;     // E : 396*256*2 = 202752 (+pad)
static constexpr size_t OFF_P  = 28542976;     // P : nch * 3145728
static constexpr size_t SLAB   = (size_t)BP * DF * 4;

// lgkm-only barrier: LDS ordered, global loads stay IN FLIGHT (no vmcnt drain)
__device__ __forceinline__ void barrier_lgkm() {
  __builtin_amdgcn_sched_barrier(0);
  asm volatile("s_waitcnt lgkmcnt(0)" ::: "memory");
  __builtin_amdgcn_s_barrier();
  __builtin_amdgcn_sched_barrier(0);
}

// ---------------- K1: x -> fp16 ----------------
__global__ void k_prep_x(const float* __restrict__ x, f16* __restrict__ xh) {
  int i = blockIdx.x * 256 + threadIdx.x;
  f32x4 v = ((const f32x4*)x)[i];
  union { f16 f[4]; short4 s; } u;
  u.f[0] = (f16)v[0]; u.f[1] = (f16)v[1]; u.f[2] = (f16)v[2]; u.f[3] = (f16)v[3];
  ((short4*)xh)[i] = u.s;
}

// ---------------- K2: S-tile via MFMA -> block softmax partials + W' ----------------
// tile 128n x 256b, 8 waves (wave 32n x 128b, acc[2][8]), K-step 32.
// 2-deep A (data HBM) / 1-deep B (xh L2) register prefetch; 1 lgkm-barrier per step.
__global__ __launch_bounds__(512, 4) void k_qk(const float* __restrict__ data,
                                               const f16* __restrict__ xh,
                                               const float* __restrict__ sigma,
                                               f16* __restrict__ W,
                                               float* __restrict__ Mp,
                                               float* __restrict__ Lp) {
  __shared__ char smem[61952];
  f16 (*As)[5120]  = (f16(*)[5120])smem;              // 2 x 10240 B : [128][40]
  f16 (*Bs)[10240] = (f16(*)[10240])(smem + 20480);   // 2 x 20480 B : [256][40]
  float* dn_s = (float*)(smem + 61440);               // [128]
  float* m4   = (float*)smem;                         // alias: [4][256]
  float* l4   = (float*)(smem + 4096);                // alias: [4][256]
  float* m_s  = (float*)(smem + 8192);                // alias: [256]
  f16*  trans = (f16*)(smem + 20480);                 // alias: [256][72]

  const int tid = threadIdx.x;
  const int wid = tid >> 6, lane = tid & 63;
  const int l15 = lane & 15, kg = lane >> 4;
  const int wr = wid >> 1, wb = wid & 1;
  const int n0 = blockIdx.x * 128;

  // A staging: row = tid>>2 (128 rows), 8 floats at (tid&3)*8
  const int arow = tid >> 2, ak = (tid & 3) * 8;
  const int ar_g = n0 + arow;
  const float* ap = data + (size_t)(ar_g < NDATA ? ar_g : NDATA - 1) * DF + ak;
  // B staging: row = tid>>1 (256 rows), 16 f16 at (tid&1)*16
  const int brow = tid >> 1, bk = (tid & 1) * 16;
  const f16* bp = xh + (size_t)brow * DF + bk;

  f32x4 acc[2][8] = {};
  float sq = 0.f;
  f32x4 a0A, a1A, a0B, a1B;     // two A prefetch sets
  f16x8 rb0, rb1;               // one B prefetch set

  auto gloadA = [&](int k0, f32x4& a0, f32x4& a1) {
    a0 = *(const f32x4*)(ap + k0);
    a1 = *(const f32x4*)(ap + k0 + 4);
  };
  auto gloadB = [&](int k0) {
    rb0 = *(const f16x8*)(bp + k0);
    rb1 = *(const f16x8*)(bp + k0 + 8);
  };
  auto swriteA = [&](int buf, f32x4& a0, f32x4& a1) {
    f16x8 h;
#pragma unroll
    for (int j = 0; j < 4; ++j) {
      h[j] = (f16)a0[j];     sq = fmaf(a0[j], a0[j], sq);
      h[4 + j] = (f16)a1[j]; sq = fmaf(a1[j], a1[j], sq);
    }
    *(f16x8*)(&As[buf][arow * 40 + ak]) = h;
  };
  auto swriteB = [&](int buf) {
    *(f16x8*)(&Bs[buf][brow * 40 + bk]) = rb0;
    *(f16x8*)(&Bs[buf][brow * 40 + bk + 8]) = rb1;
  };
  auto compute = [&](int buf) {
    f16x8 af0 = *(const f16x8*)(&As[buf][(wr * 32 + l15) * 40 + kg * 8]);
    f16x8 af1 = *(const f16x8*)(&As[buf][(wr * 32 + 16 + l15) * 40 + kg * 8]);
#pragma unroll
    for (int c = 0; c < 8; ++c) {
      f16x8 bf = *(const f16x8*)(&Bs[buf][(wb * 128 + c * 16 + l15) * 40 + kg * 8]);
      acc[0][c] = __builtin_amdgcn_mfma_f32_16x16x32_f16(af0, bf, acc[0][c], 0, 0, 0);
      acc[1][c] = __builtin_amdgcn_mfma_f32_16x16x32_f16(af1, bf, acc[1][c], 0, 0, 0);
    }
  };

  gloadA(0, a0A, a1A);
  gloadB(0);
  swriteA(0, a0A, a1A);
  swriteB(0);
  gloadA(32, a0B, a1B);
  barrier_lgkm();

  for (int ks = 0; ks < 96; ks += 2) {
    // step ks (buf 0)
    if (ks + 2 < 96) gloadA((ks + 2) * 32, a0A, a1A);
    gloadB((ks + 1) * 32);                 // ks+1 <= 95 always
    compute(0);
    swriteA(1, a0B, a1B);                  // step ks+1 data
    swriteB(1);
    barrier_lgkm();
    // step ks+1 (buf 1)
    if (ks + 3 < 96) { gloadA((ks + 3) * 32, a0B, a1B); }
    if (ks + 2 < 96) { gloadB((ks + 2) * 32); }
    compute(1);
    if (ks + 2 < 96) { swriteA(0, a0A, a1A); swriteB(0); }
    barrier_lgkm();
  }

  // |d|^2: reduce over 4 k-quarter threads of each row
  sq += __shfl_xor(sq, 1);
  sq += __shfl_xor(sq, 2);
  if ((lane & 3) == 0) dn_s[arow] = sq;
  __syncthreads();

  const float sg  = sigma[0];
  const float inv = 0.5f / (sg * sg);
  float dn[2][4];
  bool ok[2][4];
#pragma unroll
  for (int i = 0; i < 2; ++i)
#pragma unroll
    for (int r = 0; r < 4; ++r) {
      int rl = wr * 32 + i * 16 + kg * 4 + r;
      dn[i][r] = dn_s[rl];
      ok[i][r] = (n0 + rl) < NDATA;
    }

  // pass 1: block-local column max
  float pm[8];
#pragma unroll
  for (int c = 0; c < 8; ++c) pm[c] = -1e30f;
#pragma unroll
  for (int i = 0; i < 2; ++i)
#pragma unroll
    for (int r = 0; r < 4; ++r)
#pragma unroll
      for (int c = 0; c < 8; ++c) {
        float v = ok[i][r] ? (2.f * acc[i][c][r] - dn[i][r]) * inv : -1e30f;
        pm[c] = fmaxf(pm[c], v);
      }
#pragma unroll
  for (int c = 0; c < 8; ++c) {
    pm[c] = fmaxf(pm[c], __shfl_xor(pm[c], 16));
    pm[c] = fmaxf(pm[c], __shfl_xor(pm[c], 32));
  }
  if (kg == 0) {
#pragma unroll
    for (int c = 0; c < 8; ++c) m4[wr * 256 + wb * 128 + c * 16 + l15] = pm[c];
  }
  __syncthreads();
  if (tid < 256)
    m_s[tid] = fmaxf(fmaxf(m4[tid], m4[256 + tid]), fmaxf(m4[512 + tid], m4[768 + tid]));
  __syncthreads();

  float mcol[8];
#pragma unroll
  for (int c = 0; c < 8; ++c) mcol[c] = m_s[wb * 128 + c * 16 + l15];

  // pass 2: two 64-n chunks through the trans buffer
  float pl[8] = {};
#pragma unroll
  for (int h = 0; h < 2; ++h) {
    if ((wr >> 1) == h) {
#pragma unroll
      for (int i = 0; i < 2; ++i)
#pragma unroll
        for (int r = 0; r < 4; ++r) {
          const int rl2 = (wr & 1) * 32 + i * 16 + kg * 4 + r;
#pragma unroll
          for (int c = 0; c < 8; ++c) {
            float v = (2.f * acc[i][c][r] - dn[i][r]) * inv;
            float w = ok[i][r] ? __expf(v - mcol[c]) : 0.f;
            pl[c] += w;
            trans[(wb * 128 + c * 16 + l15) * 72 + rl2] = (f16)w;
          }
        }
    }
    __syncthreads();
    {
      const int col = tid >> 1, q = tid & 1;
      const f16* src = trans + col * 72 + q * 32;
      f16* dst = W + (size_t)col * NW + n0 + h * 64 + q * 32;
#pragma unroll
      for (int j = 0; j < 4; ++j)
        *(f16x8*)(dst + j * 8) = *(const f16x8*)(src + j * 8);
    }
    __syncthreads();
  }

#pragma unroll
  for (int c = 0; c < 8; ++c) {
    pl[c] += __shfl_xor(pl[c], 16);
    pl[c] += __shfl_xor(pl[c], 32);
  }
  if (kg == 0) {
#pragma unroll
    for (int c = 0; c < 8; ++c) l4[wr * 256 + wb * 128 + c * 16 + l15] = pl[c];
  }
  __syncthreads();
  if (tid < 256) {
    Mp[blockIdx.x * 256 + tid] = m_s[tid];
    Lp[blockIdx.x * 256 + tid] = l4[tid] + l4[256 + tid] + l4[512 + tid] + l4[768 + tid];
  }
}

// ---------------- K3: combine partials -> M[b], L[b] ----------------
__global__ void k_comb(const float* __restrict__ Mp, const float* __restrict__ Lp,
                       float* __restrict__ M, float* __restrict__ L, int ngrp) {
  __shared__ float ms[4][256], ls[4][256];
  const int tid = threadIdx.x;
  const int q = tid >> 8, b = tid & 255;
  float m = -1e38f, l = 0.f;
  for (int g = q; g < ngrp; g += 4) {
    float m2 = Mp[g * 256 + b], l2 = Lp[g * 256 + b];
    if (m2 > m) { l = l * __expf(m - m2) + l2; m = m2; }
    else        { l += l2 * __expf(m2 - m); }
  }
  ms[q][b] = m; ls[q][b] = l;
  __syncthreads();
  if (q == 0) {
#pragma unroll
    for (int j = 1; j < 4; ++j) {
      float m2 = ms[j][b], l2 = ls[j][b];
      if (m2 > m) { l = l * __expf(m - m2) + l2; m = m2; }
      else        { l += l2 * __expf(m2 - m); }
    }
    M[b] = m; L[b] = l;
  }
}

// ---------------- K3b: E[g][b] = (f16)exp(Mp - M)  (203 KB, L2-resident) ----------------
__global__ void k_exp(const float* __restrict__ Mp, const float* __restrict__ M,
                      f16* __restrict__ E) {
  const int g = blockIdx.x;
  const int b = threadIdx.x;
  E[g * 256 + b] = (f16)__expf(Mp[g * 256 + b] - M[b]);
}

// ---------------- K4: eps partials = (W*E) @ data, split-K over n ----------------
// 512 thr, tile 256b x 64d, K-step 32. Rescale factor loaded as precomputed f16
// (branchless, no transcendental on the critical path).
__global__ __launch_bounds__(512, 4) void k_pv(const float* __restrict__ data,
                                               const f16* __restrict__ W,
                                               const f16* __restrict__ E,
                                               float* __restrict__ part,
                                               int chn, int per8) {
  __shared__ f16 T[2][64 * 40];   // [d][n(32)+pad]
  const int tid = threadIdx.x;
  const int wid = tid >> 6, lane = tid & 63;
  const int l15 = lane & 15, kg = lane >> 4;
  const int bid = blockIdx.x;
  const int swz = (bid & 7) * per8 + (bid >> 3);   // XCD-chunked (grid % 8 == 0)
  const int chunk = swz / NDT2;
  const int dt = swz % NDT2;
  const int d0 = dt * 64;
  const int nstart = chunk * chn;
  const int kst = chn >> 5;
  const int nl = tid >> 4, dl = (tid & 15) * 4;    // staging: 32 n-rows x 64 d (exact)

  f32x4 acc[2][4] = {};
  const int b0 = wid * 32 + l15, b1 = b0 + 16;
  const f16* wp0 = W + (size_t)b0 * NW + nstart + kg * 8;
  const f16* wp1 = W + (size_t)b1 * NW + nstart + kg * 8;

  f32x4 gA, gB;
  f16x8 w0c, w1c, w0n, w1n;
  f16 hAc, hBc, hAn, hBn;

  auto gload = [&](int ks, f32x4& g) {
    int row = nstart + ks * 32 + nl;
    int rc = row < NDATA ? row : NDATA - 1;        // tail rows have W==0
    g = *(const f32x4*)(data + (size_t)rc * DF + d0 + dl);
  };
  auto wload = [&](int ks, f16x8& w0, f16x8& w1, f16& ha, f16& hb) {
    w0 = *(const f16x8*)(wp0 + ks * 32);
    w1 = *(const f16x8*)(wp1 + ks * 32);
    int gq = (nstart + ks * 32) >> 7;              // 128-row Mp groups
    ha = E[gq * 256 + b0];
    hb = E[gq * 256 + b1];
  };
  auto twrite = [&](int buf, f32x4& g) {
#pragma unroll
    for (int j = 0; j < 4; ++j) {
      int d = dl + j;                              // d <= 63: in-bounds
      int pn = nl ^ (((d >> 3) & 3) << 3);         // bank swizzle
      T[buf][d * 40 + pn] = (f16)g[j];
    }
  };
  auto compute = [&](int buf, f16x8& w0, f16x8& w1, f16 h0, f16 h1) {
    f16x8 a0, a1;
#pragma unroll
    for (int j = 0; j < 8; ++j) { a0[j] = w0[j] * h0; a1[j] = w1[j] * h1; }
#pragma unroll
    for (int c = 0; c < 4; ++c) {
      int d = c * 16 + l15;
      int pb = (kg * 8) ^ (((d >> 3) & 3) << 3);
      f16x8 bf = *(const f16x8*)(&T[buf][d * 40 + pb]);
      acc[0][c] = __builtin_amdgcn_mfma_f32_16x16x32_f16(a0, bf, acc[0][c], 0, 0, 0);
      acc[1][c] = __builtin_amdgcn_mfma_f32_16x16x32_f16(a1, bf, acc[1][c], 0, 0, 0);
    }
  };

  gload(0, gA);
  wload(0, w0c, w1c, hAc, hBc);
  twrite(0, gA);
  gload(1, gB);
  barrier_lgkm();

  for (int ks = 0; ks < kst; ks += 2) {
    if (ks + 2 < kst) gload(ks + 2, gA);           // data 2 ahead
    if (ks + 1 < kst) wload(ks + 1, w0n, w1n, hAn, hBn);
    compute(0, w0c, w1c, hAc, hBc);
    if (ks + 1 < kst) twrite(1, gB);               // step ks+1 data
    barrier_lgkm();
    if (ks + 1 < kst) {
      if (ks + 3 < kst) gload(ks + 3, gB);
      if (ks + 2 < kst) wload(ks + 2, w0c, w1c, hAc, hBc);
      compute(1, w0n, w1n, hAn, hBn);
      if (ks + 2 < kst) twrite(0, gA);             // step ks+2 data
      barrier_lgkm();
    }
  }

  float* pp = part + (size_t)chunk * (BP * DF);
#pragma unroll
  for (int i = 0; i < 2; ++i)
#pragma unroll
    for (int c = 0; c < 4; ++c)
#pragma unroll
      for (int r = 0; r < 4; ++r) {
        int b = wid * 32 + i * 16 + kg * 4 + r;
        int d = d0 + c * 16 + l15;
        pp[(size_t)b * DF + d] = acc[i][c][r];
      }
}

// ---------------- K5: out = (x - (sum partials)/L) / sigma ----------------
__global__ void k_final(const float* __restrict__ x, const float* __restrict__ sigma,
                        const float* __restrict__ part, const float* __restrict__ L,
                        float* __restrict__ out, int nch) {
  int i = blockIdx.x * 256 + threadIdx.x;
  int b = (i * 4) / DF;
  f32x4 s = {};
  for (int c = 0; c < nch; ++c) s += ((const f32x4*)(part + (size_t)c * BP * DF))[i];
  f32x4 xv = ((const f32x4*)x)[i];
  float invL = 1.f / L[b];
  float invsg = 1.f / sigma[0];
  f32x4 r;
#pragma unroll
  for (int j = 0; j < 4; ++j) r[j] = (xv[j] - s[j] * invL) * invsg;
  ((f32x4*)out)[i] = r;
}

extern "C" void kernel_launch(void* const* d_in, const int* in_sizes, int n_in,
                              void* d_out, int out_size, void* d_ws, size_t ws_size,
                              hipStream_t stream) {
  const float* x     = (const float*)d_in[0];
  const float* sigma = (const float*)d_in[1];
  const float* data  = (const float*)d_in[2];
  float* out = (float*)d_out;
  char* ws = (char*)d_ws;

  f16*   W  = (f16*)(ws + OFF_W);
  f16*   xh = (f16*)(ws + OFF_XH);
  float* Mp = (float*)(ws + OFF_MP);
  float* Lp = (float*)(ws + OFF_LP);
  float* M  = (float*)(ws + OFF_M);
  float* L  = (float*)(ws + OFF_L);
  f16*   E  = (f16*)(ws + OFF_E);
  float* P  = (float*)(ws + OFF_P);

  int nch = 24, chn = 2112;                         // 24*2112 = 50688 exactly
  if (ws_size < OFF_P + 24 * SLAB) { nch = 16; chn = 3168; }
  if (ws_size < OFF_P + 16 * SLAB) { nch = 8;  chn = 6336; }
  const int grid_pv = NDT2 * nch;
  const int per8 = grid_pv / 8;

  k_prep_x<<<768, 256, 0, stream>>>(x, xh);
  k_qk<<<NGRPQ, 512, 0, stream>>>(data, xh, sigma, W, Mp, Lp);
  k_comb<<<1, 1024, 0, stream>>>(Mp, Lp, M, L, NGRPQ);
  k_exp<<<NGRPQ, 256, 0, stream>>>(Mp, M, E);
  k_pv<<<grid_pv, 512, 0, stream>>>(data, W, E, P, chn, per8);
  k_final<<<768, 256, 0, stream>>>(x, sigma, P, L, out, nch);
}

// Round 13
// 500.478 us; speedup vs baseline: 1.5598x; 1.0445x over previous
//
#include <hip/hip_runtime.h>

typedef _Float16 f16;
typedef f16 f16x8 __attribute__((ext_vector_type(8)));
typedef float f32x4 __attribute__((ext_vector_type(4)));

static constexpr int NDATA = 50000;
static constexpr int DF    = 3072;
static constexpr int BP    = 256;
static constexpr int NW    = 50688;   // W row stride / padded N (396*128)
static constexpr int NGRPQ = 396;     // k_qk blocks = softmax groups (128 n each)
static constexpr int NDT3  = 24;      // d-tiles of 128 in k_pv

// workspace offsets (bytes)
static constexpr size_t OFF_W  = 0;            // W : 256*50688*2 = 25952256
static constexpr size_t OFF_XH = 25952256;     // xh: 1572864
static constexpr size_t OFF_MP = 27525120;     // Mp: 396*256*4 = 405504
static constexpr size_t OFF_LP = 27930624;     // Lp: 405504
static constexpr size_t OFF_M  = 28336128;     // M : 1024
static constexpr size_t OFF_L  = 28337152;     // L : 1024
static constexpr size_t OFF_E  = 28338176;     // E : 396*256*2 = 202752 (+pad)
static constexpr size_t OFF_P  = 28542976;     // P : nch * 3145728
static constexpr size_t SLAB   = (size_t)BP * DF * 4;

// lgkm-only barrier: LDS ordered, global loads stay IN FLIGHT (no vmcnt drain)
__device__ __forceinline__ void barrier_lgkm() {
  __builtin_amdgcn_sched_barrier(0);
  asm volatile("s_waitcnt lgkmcnt(0)" ::: "memory");
  __builtin_amdgcn_s_barrier();
  __builtin_amdgcn_sched_barrier(0);
}

// ---------------- K1: x -> fp16 ----------------
__global__ void k_prep_x(const float* __restrict__ x, f16* __restrict__ xh) {
  int i = blockIdx.x * 256 + threadIdx.x;
  f32x4 v = ((const f32x4*)x)[i];
  union { f16 f[4]; short4 s; } u;
  u.f[0] = (f16)v[0]; u.f[1] = (f16)v[1]; u.f[2] = (f16)v[2]; u.f[3] = (f16)v[3];
  ((short4*)xh)[i] = u.s;
}

// ---------------- K2: S-tile via MFMA -> block softmax partials + W' ----------------
// tile 128n x 256b, 8 waves (wave 32n x 128b, acc[2][8]), K-step 32.
// 2-deep A (data HBM) / 1-deep B (xh L2) register prefetch; 1 lgkm-barrier per step.
__global__ __launch_bounds__(512, 4) void k_qk(const float* __restrict__ data,
                                               const f16* __restrict__ xh,
                                               const float* __restrict__ sigma,
                                               f16* __restrict__ W,
                                               float* __restrict__ Mp,
                                               float* __restrict__ Lp) {
  __shared__ char smem[61952];
  f16 (*As)[5120]  = (f16(*)[5120])smem;              // 2 x 10240 B : [128][40]
  f16 (*Bs)[10240] = (f16(*)[10240])(smem + 20480);   // 2 x 20480 B : [256][40]
  float* dn_s = (float*)(smem + 61440);               // [128]
  float* m4   = (float*)smem;                         // alias: [4][256]
  float* l4   = (float*)(smem + 4096);                // alias: [4][256]
  float* m_s  = (float*)(smem + 8192);                // alias: [256]
  f16*  trans = (f16*)(smem + 20480);                 // alias: [256][72]

  const int tid = threadIdx.x;
  const int wid = tid >> 6, lane = tid & 63;
  const int l15 = lane & 15, kg = lane >> 4;
  const int wr = wid >> 1, wb = wid & 1;
  const int n0 = blockIdx.x * 128;

  // A staging: row = tid>>2 (128 rows), 8 floats at (tid&3)*8
  const int arow = tid >> 2, ak = (tid & 3) * 8;
  const int ar_g = n0 + arow;
  const float* ap = data + (size_t)(ar_g < NDATA ? ar_g : NDATA - 1) * DF + ak;
  // B staging: row = tid>>1 (256 rows), 16 f16 at (tid&1)*16
  const int brow = tid >> 1, bk = (tid & 1) * 16;
  const f16* bp = xh + (size_t)brow * DF + bk;

  f32x4 acc[2][8] = {};
  float sq = 0.f;
  f32x4 a0A, a1A, a0B, a1B;     // two A prefetch sets
  f16x8 rb0, rb1;               // one B prefetch set

  auto gloadA = [&](int k0, f32x4& a0, f32x4& a1) {
    a0 = *(const f32x4*)(ap + k0);
    a1 = *(const f32x4*)(ap + k0 + 4);
  };
  auto gloadB = [&](int k0) {
    rb0 = *(const f16x8*)(bp + k0);
    rb1 = *(const f16x8*)(bp + k0 + 8);
  };
  auto swriteA = [&](int buf, f32x4& a0, f32x4& a1) {
    f16x8 h;
#pragma unroll
    for (int j = 0; j < 4; ++j) {
      h[j] = (f16)a0[j];     sq = fmaf(a0[j], a0[j], sq);
      h[4 + j] = (f16)a1[j]; sq = fmaf(a1[j], a1[j], sq);
    }
    *(f16x8*)(&As[buf][arow * 40 + ak]) = h;
  };
  auto swriteB = [&](int buf) {
    *(f16x8*)(&Bs[buf][brow * 40 + bk]) = rb0;
    *(f16x8*)(&Bs[buf][brow * 40 + bk + 8]) = rb1;
  };
  auto compute = [&](int buf) {
    f16x8 af0 = *(const f16x8*)(&As[buf][(wr * 32 + l15) * 40 + kg * 8]);
    f16x8 af1 = *(const f16x8*)(&As[buf][(wr * 32 + 16 + l15) * 40 + kg * 8]);
#pragma unroll
    for (int c = 0; c < 8; ++c) {
      f16x8 bf = *(const f16x8*)(&Bs[buf][(wb * 128 + c * 16 + l15) * 40 + kg * 8]);
      acc[0][c] = __builtin_amdgcn_mfma_f32_16x16x32_f16(af0, bf, acc[0][c], 0, 0, 0);
      acc[1][c] = __builtin_amdgcn_mfma_f32_16x16x32_f16(af1, bf, acc[1][c], 0, 0, 0);
    }
  };

  gloadA(0, a0A, a1A);
  gloadB(0);
  swriteA(0, a0A, a1A);
  swriteB(0);
  gloadA(32, a0B, a1B);
  barrier_lgkm();

  for (int ks = 0; ks < 96; ks += 2) {
    // step ks (buf 0)
    if (ks + 2 < 96) gloadA((ks + 2) * 32, a0A, a1A);
    gloadB((ks + 1) * 32);                 // ks+1 <= 95 always
    compute(0);
    swriteA(1, a0B, a1B);                  // step ks+1 data
    swriteB(1);
    barrier_lgkm();
    // step ks+1 (buf 1)
    if (ks + 3 < 96) { gloadA((ks + 3) * 32, a0B, a1B); }
    if (ks + 2 < 96) { gloadB((ks + 2) * 32); }
    compute(1);
    if (ks + 2 < 96) { swriteA(0, a0A, a1A); swriteB(0); }
    barrier_lgkm();
  }

  // |d|^2: reduce over 4 k-quarter threads of each row
  sq += __shfl_xor(sq, 1);
  sq += __shfl_xor(sq, 2);
  if ((lane & 3) == 0) dn_s[arow] = sq;
  __syncthreads();

  const float sg  = sigma[0];
  const float inv = 0.5f / (sg * sg);
  float dn[2][4];
  bool ok[2][4];
#pragma unroll
  for (int i = 0; i < 2; ++i)
#pragma unroll
    for (int r = 0; r < 4; ++r) {
      int rl = wr * 32 + i * 16 + kg * 4 + r;
      dn[i][r] = dn_s[rl];
      ok[i][r] = (n0 + rl) < NDATA;
    }

  // pass 1: block-local column max
  float pm[8];
#pragma unroll
  for (int c = 0; c < 8; ++c) pm[c] = -1e30f;
#pragma unroll
  for (int i = 0; i < 2; ++i)
#pragma unroll
    for (int r = 0; r < 4; ++r)
#pragma unroll
      for (int c = 0; c < 8; ++c) {
        float v = ok[i][r] ? (2.f * acc[i][c][r] - dn[i][r]) * inv : -1e30f;
        pm[c] = fmaxf(pm[c], v);
      }
#pragma unroll
  for (int c = 0; c < 8; ++c) {
    pm[c] = fmaxf(pm[c], __shfl_xor(pm[c], 16));
    pm[c] = fmaxf(pm[c], __shfl_xor(pm[c], 32));
  }
  if (kg == 0) {
#pragma unroll
    for (int c = 0; c < 8; ++c) m4[wr * 256 + wb * 128 + c * 16 + l15] = pm[c];
  }
  __syncthreads();
  if (tid < 256)
    m_s[tid] = fmaxf(fmaxf(m4[tid], m4[256 + tid]), fmaxf(m4[512 + tid], m4[768 + tid]));
  __syncthreads();

  float mcol[8];
#pragma unroll
  for (int c = 0; c < 8; ++c) mcol[c] = m_s[wb * 128 + c * 16 + l15];

  // pass 2: two 64-n chunks through the trans buffer
  float pl[8] = {};
#pragma unroll
  for (int h = 0; h < 2; ++h) {
    if ((wr >> 1) == h) {
#pragma unroll
      for (int i = 0; i < 2; ++i)
#pragma unroll
        for (int r = 0; r < 4; ++r) {
          const int rl2 = (wr & 1) * 32 + i * 16 + kg * 4 + r;
#pragma unroll
          for (int c = 0; c < 8; ++c) {
            float v = (2.f * acc[i][c][r] - dn[i][r]) * inv;
            float w = ok[i][r] ? __expf(v - mcol[c]) : 0.f;
            pl[c] += w;
            trans[(wb * 128 + c * 16 + l15) * 72 + rl2] = (f16)w;
          }
        }
    }
    __syncthreads();
    {
      const int col = tid >> 1, q = tid & 1;
      const f16* src = trans + col * 72 + q * 32;
      f16* dst = W + (size_t)col * NW + n0 + h * 64 + q * 32;
#pragma unroll
      for (int j = 0; j < 4; ++j)
        *(f16x8*)(dst + j * 8) = *(const f16x8*)(src + j * 8);
    }
    __syncthreads();
  }

#pragma unroll
  for (int c = 0; c < 8; ++c) {
    pl[c] += __shfl_xor(pl[c], 16);
    pl[c] += __shfl_xor(pl[c], 32);
  }
  if (kg == 0) {
#pragma unroll
    for (int c = 0; c < 8; ++c) l4[wr * 256 + wb * 128 + c * 16 + l15] = pl[c];
  }
  __syncthreads();
  if (tid < 256) {
    Mp[blockIdx.x * 256 + tid] = m_s[tid];
    Lp[blockIdx.x * 256 + tid] = l4[tid] + l4[256 + tid] + l4[512 + tid] + l4[768 + tid];
  }
}

// ---------------- K3: combine partials -> M[b], L[b] ----------------
__global__ void k_comb(const float* __restrict__ Mp, const float* __restrict__ Lp,
                       float* __restrict__ M, float* __restrict__ L, int ngrp) {
  __shared__ float ms[4][256], ls[4][256];
  const int tid = threadIdx.x;
  const int q = tid >> 8, b = tid & 255;
  float m = -1e38f, l = 0.f;
  for (int g = q; g < ngrp; g += 4) {
    float m2 = Mp[g * 256 + b], l2 = Lp[g * 256 + b];
    if (m2 > m) { l = l * __expf(m - m2) + l2; m = m2; }
    else        { l += l2 * __expf(m2 - m); }
  }
  ms[q][b] = m; ls[q][b] = l;
  __syncthreads();
  if (q == 0) {
#pragma unroll
    for (int j = 1; j < 4; ++j) {
      float m2 = ms[j][b], l2 = ls[j][b];
      if (m2 > m) { l = l * __expf(m - m2) + l2; m = m2; }
      else        { l += l2 * __expf(m2 - m); }
    }
    M[b] = m; L[b] = l;
  }
}

// ---------------- K3b: E[g][b] = (f16)exp(Mp - M)  (203 KB, L2-resident) ----------------
__global__ void k_exp(const float* __restrict__ Mp, const float* __restrict__ M,
                      f16* __restrict__ E) {
  const int g = blockIdx.x;
  const int b = threadIdx.x;
  E[g * 256 + b] = (f16)__expf(Mp[g * 256 + b] - M[b]);
}

// ---------------- K4: eps partials = (W*E) @ data, split-K over n ----------------
// 512 thr, tile 256b x 128d (wave 32b x 128d, acc[2][8]), K-step 32.
// Halves W L2 re-reads and barriers/FLOP vs the 64-d tile. Staging: 8 floats/thread
// covering 32n x 128d exactly (T has 128 d-rows: in-bounds).
__global__ __launch_bounds__(512, 4) void k_pv(const float* __restrict__ data,
                                               const f16* __restrict__ W,
                                               const f16* __restrict__ E,
                                               float* __restrict__ part,
                                               int chn, int per8) {
  __shared__ f16 T[2][128 * 40];   // [d][n(32)+pad]
  const int tid = threadIdx.x;
  const int wid = tid >> 6, lane = tid & 63;
  const int l15 = lane & 15, kg = lane >> 4;
  const int bid = blockIdx.x;
  const int swz = (bid & 7) * per8 + (bid >> 3);   // XCD-chunked (grid % 8 == 0)
  const int chunk = swz / NDT3;
  const int dt = swz % NDT3;
  const int d0 = dt * 128;
  const int nstart = chunk * chn;
  const int kst = chn >> 5;
  const int nl = tid >> 4, dl = (tid & 15) * 8;    // staging: 32 n-rows x 128 d (exact)

  f32x4 acc[2][8] = {};
  const int b0 = wid * 32 + l15, b1 = b0 + 16;
  const f16* wp0 = W + (size_t)b0 * NW + nstart + kg * 8;
  const f16* wp1 = W + (size_t)b1 * NW + nstart + kg * 8;

  f32x4 gA0, gA1, gB0, gB1;      // two data prefetch sets (even / odd steps)
  f16x8 w0c, w1c, w0n, w1n;
  f16 hAc, hBc, hAn, hBn;

  auto gload = [&](int ks, f32x4& g0, f32x4& g1) {
    int row = nstart + ks * 32 + nl;
    int rc = row < NDATA ? row : NDATA - 1;        // tail rows have W==0
    const float* gp = data + (size_t)rc * DF + d0 + dl;
    g0 = *(const f32x4*)gp;
    g1 = *(const f32x4*)(gp + 4);
  };
  auto wload = [&](int ks, f16x8& w0, f16x8& w1, f16& ha, f16& hb) {
    w0 = *(const f16x8*)(wp0 + ks * 32);
    w1 = *(const f16x8*)(wp1 + ks * 32);
    int gq = (nstart + ks * 32) >> 7;              // 128-row Mp groups (chn % 128 == 0)
    ha = E[gq * 256 + b0];
    hb = E[gq * 256 + b1];
  };
  auto twrite = [&](int buf, f32x4& g0, f32x4& g1) {
#pragma unroll
    for (int j = 0; j < 8; ++j) {
      float v = (j < 4) ? g0[j] : g1[j - 4];
      int d = dl + j;                              // d <= 127: in-bounds (T is 128 rows)
      int pn = nl ^ (((d >> 3) & 3) << 3);         // bank swizzle
      T[buf][d * 40 + pn] = (f16)v;
    }
  };
  auto compute = [&](int buf, f16x8& w0, f16x8& w1, f16 h0, f16 h1) {
    f16x8 a0, a1;
#pragma unroll
    for (int j = 0; j < 8; ++j) { a0[j] = w0[j] * h0; a1[j] = w1[j] * h1; }
#pragma unroll
    for (int c = 0; c < 8; ++c) {
      int d = c * 16 + l15;
      int pb = (kg * 8) ^ (((d >> 3) & 3) << 3);
      f16x8 bf = *(const f16x8*)(&T[buf][d * 40 + pb]);
      acc[0][c] = __builtin_amdgcn_mfma_f32_16x16x32_f16(a0, bf, acc[0][c], 0, 0, 0);
      acc[1][c] = __builtin_amdgcn_mfma_f32_16x16x32_f16(a1, bf, acc[1][c], 0, 0, 0);
    }
  };

  gload(0, gA0, gA1);
  wload(0, w0c, w1c, hAc, hBc);
  twrite(0, gA0, gA1);
  gload(1, gB0, gB1);
  barrier_lgkm();

  for (int ks = 0; ks < kst; ks += 2) {
    if (ks + 2 < kst) gload(ks + 2, gA0, gA1);     // data 2 ahead
    if (ks + 1 < kst) wload(ks + 1, w0n, w1n, hAn, hBn);
    compute(0, w0c, w1c, hAc, hBc);
    if (ks + 1 < kst) twrite(1, gB0, gB1);         // step ks+1 data
    barrier_lgkm();
    if (ks + 1 < kst) {
      if (ks + 3 < kst) gload(ks + 3, gB0, gB1);
      if (ks + 2 < kst) wload(ks + 2, w0c, w1c, hAc, hBc);
      compute(1, w0n, w1n, hAn, hBn);
      if (ks + 2 < kst) twrite(0, gA0, gA1);       // step ks+2 data
      barrier_lgkm();
    }
  }

  float* pp = part + (size_t)chunk * (BP * DF);
#pragma unroll
  for (int i = 0; i < 2; ++i)
#pragma unroll
    for (int c = 0; c < 8; ++c)
#pragma unroll
      for (int r = 0; r < 4; ++r) {
        int b = wid * 32 + i * 16 + kg * 4 + r;
        int d = d0 + c * 16 + l15;
        pp[(size_t)b * DF + d] = acc[i][c][r];
      }
}

// ---------------- K5: out = (x - (sum partials)/L) / sigma ----------------
__global__ void k_final(const float* __restrict__ x, const float* __restrict__ sigma,
                        const float* __restrict__ part, const float* __restrict__ L,
                        float* __restrict__ out, int nch) {
  int i = blockIdx.x * 256 + threadIdx.x;
  int b = (i * 4) / DF;
  f32x4 s = {};
  for (int c = 0; c < nch; ++c) s += ((const f32x4*)(part + (size_t)c * BP * DF))[i];
  f32x4 xv = ((const f32x4*)x)[i];
  float invL = 1.f / L[b];
  float invsg = 1.f / sigma[0];
  f32x4 r;
#pragma unroll
  for (int j = 0; j < 4; ++j) r[j] = (xv[j] - s[j] * invL) * invsg;
  ((f32x4*)out)[i] = r;
}

extern "C" void kernel_launch(void* const* d_in, const int* in_sizes, int n_in,
                              void* d_out, int out_size, void* d_ws, size_t ws_size,
                              hipStream_t stream) {
  const float* x     = (const float*)d_in[0];
  const float* sigma = (const float*)d_in[1];
  const float* data  = (const float*)d_in[2];
  float* out = (float*)d_out;
  char* ws = (char*)d_ws;

  f16*   W  = (f16*)(ws + OFF_W);
  f16*   xh = (f16*)(ws + OFF_XH);
  float* Mp = (float*)(ws + OFF_MP);
  float* Lp = (float*)(ws + OFF_LP);
  float* M  = (float*)(ws + OFF_M);
  float* L  = (float*)(ws + OFF_L);
  f16*   E  = (f16*)(ws + OFF_E);
  float* P  = (float*)(ws + OFF_P);

  // split-K width: 22 x 2304 = 50688 exactly (2304 % 128 == 0 for Mp groups)
  int nch = 22, chn = 2304;
  if (ws_size < OFF_P + 22 * SLAB) { nch = 16; chn = 3168; }
  if (ws_size < OFF_P + 16 * SLAB) { nch = 8;  chn = 6336; }
  const int grid_pv = NDT3 * nch;                   // 528 / 384 / 192 — all % 8 == 0
  const int per8 = grid_pv / 8;

  k_prep_x<<<768, 256, 0, stream>>>(x, xh);
  k_qk<<<NGRPQ, 512, 0, stream>>>(data, xh, sigma, W, Mp, Lp);
  k_comb<<<1, 1024, 0, stream>>>(Mp, Lp, M, L, NGRPQ);
  k_exp<<<NGRPQ, 256, 0, stream>>>(Mp, M, E);
  k_pv<<<grid_pv, 512, 0, stream>>>(data, W, E, P, chn, per8);
  k_final<<<768, 256, 0, stream>>>(x, sigma, P, L, out, nch);
}

// Round 14
// 463.886 us; speedup vs baseline: 1.6828x; 1.0789x over previous
//
#include <hip/hip_runtime.h>

typedef _Float16 f16;
typedef f16 f16x8 __attribute__((ext_vector_type(8)));
typedef float f32x4 __attribute__((ext_vector_type(4)));

static constexpr int NDATA = 50000;
static constexpr int DF    = 3072;
static constexpr int BP    = 256;
static constexpr int NW    = 50688;   // W row stride / padded N (396*128)
static constexpr int NGRPQ = 396;     // k_qk blocks = softmax groups (128 n each)
static constexpr int NDT3  = 24;      // d-tiles of 128 in k_pv

// workspace offsets (bytes)
static constexpr size_t OFF_W  = 0;            // W : 256*50688*2 = 25952256
static constexpr size_t OFF_XH = 25952256;     // xh: 1572864
static constexpr size_t OFF_MP = 27525120;     // Mp: 396*256*4 = 405504
static constexpr size_t OFF_LP = 27930624;     // Lp: 405504
static constexpr size_t OFF_M  = 28336128;     // M : 1024
static constexpr size_t OFF_L  = 28337152;     // L : 1024
static constexpr size_t OFF_E  = 28338176;     // E : 396*256*2 = 202752 (+pad)
static constexpr size_t OFF_P  = 28542976;     // P : nch * 3145728
static constexpr size_t SLAB   = (size_t)BP * DF * 4;

// lgkm-only barrier: LDS ordered, global loads stay IN FLIGHT (no vmcnt drain)
__device__ __forceinline__ void barrier_lgkm() {
  __builtin_amdgcn_sched_barrier(0);
  asm volatile("s_waitcnt lgkmcnt(0)" ::: "memory");
  __builtin_amdgcn_s_barrier();
  __builtin_amdgcn_sched_barrier(0);
}

// ---------------- K1: x -> fp16 ----------------
__global__ void k_prep_x(const float* __restrict__ x, f16* __restrict__ xh) {
  int i = blockIdx.x * 256 + threadIdx.x;
  f32x4 v = ((const f32x4*)x)[i];
  union { f16 f[4]; short4 s; } u;
  u.f[0] = (f16)v[0]; u.f[1] = (f16)v[1]; u.f[2] = (f16)v[2]; u.f[3] = (f16)v[3];
  ((short4*)xh)[i] = u.s;
}

// ---------------- K2: S-tile via MFMA -> block softmax partials + W' ----------------
// tile 128n x 256b, 8 waves (wave 32n x 128b, acc[2][8]), K-step 32.
// 2-deep A (data HBM) / 1-deep B (xh L2) register prefetch; 1 lgkm-barrier per step.
__global__ __launch_bounds__(512, 4) void k_qk(const float* __restrict__ data,
                                               const f16* __restrict__ xh,
                                               const float* __restrict__ sigma,
                                               f16* __restrict__ W,
                                               float* __restrict__ Mp,
                                               float* __restrict__ Lp) {
  __shared__ char smem[61952];
  f16 (*As)[5120]  = (f16(*)[5120])smem;              // 2 x 10240 B : [128][40]
  f16 (*Bs)[10240] = (f16(*)[10240])(smem + 20480);   // 2 x 20480 B : [256][40]
  float* dn_s = (float*)(smem + 61440);               // [128]
  float* m4   = (float*)smem;                         // alias: [4][256]
  float* l4   = (float*)(smem + 4096);                // alias: [4][256]
  float* m_s  = (float*)(smem + 8192);                // alias: [256]
  f16*  trans = (f16*)(smem + 20480);                 // alias: [256][72]

  const int tid = threadIdx.x;
  const int wid = tid >> 6, lane = tid & 63;
  const int l15 = lane & 15, kg = lane >> 4;
  const int wr = wid >> 1, wb = wid & 1;
  const int n0 = blockIdx.x * 128;

  // A staging: row = tid>>2 (128 rows), 8 floats at (tid&3)*8
  const int arow = tid >> 2, ak = (tid & 3) * 8;
  const int ar_g = n0 + arow;
  const float* ap = data + (size_t)(ar_g < NDATA ? ar_g : NDATA - 1) * DF + ak;
  // B staging: row = tid>>1 (256 rows), 16 f16 at (tid&1)*16
  const int brow = tid >> 1, bk = (tid & 1) * 16;
  const f16* bp = xh + (size_t)brow * DF + bk;

  f32x4 acc[2][8] = {};
  float sq = 0.f;
  f32x4 a0A, a1A, a0B, a1B;     // two A prefetch sets
  f16x8 rb0, rb1;               // one B prefetch set

  auto gloadA = [&](int k0, f32x4& a0, f32x4& a1) {
    a0 = *(const f32x4*)(ap + k0);
    a1 = *(const f32x4*)(ap + k0 + 4);
  };
  auto gloadB = [&](int k0) {
    rb0 = *(const f16x8*)(bp + k0);
    rb1 = *(const f16x8*)(bp + k0 + 8);
  };
  auto swriteA = [&](int buf, f32x4& a0, f32x4& a1) {
    f16x8 h;
#pragma unroll
    for (int j = 0; j < 4; ++j) {
      h[j] = (f16)a0[j];     sq = fmaf(a0[j], a0[j], sq);
      h[4 + j] = (f16)a1[j]; sq = fmaf(a1[j], a1[j], sq);
    }
    *(f16x8*)(&As[buf][arow * 40 + ak]) = h;
  };
  auto swriteB = [&](int buf) {
    *(f16x8*)(&Bs[buf][brow * 40 + bk]) = rb0;
    *(f16x8*)(&Bs[buf][brow * 40 + bk + 8]) = rb1;
  };
  auto compute = [&](int buf) {
    f16x8 af0 = *(const f16x8*)(&As[buf][(wr * 32 + l15) * 40 + kg * 8]);
    f16x8 af1 = *(const f16x8*)(&As[buf][(wr * 32 + 16 + l15) * 40 + kg * 8]);
#pragma unroll
    for (int c = 0; c < 8; ++c) {
      f16x8 bf = *(const f16x8*)(&Bs[buf][(wb * 128 + c * 16 + l15) * 40 + kg * 8]);
      acc[0][c] = __builtin_amdgcn_mfma_f32_16x16x32_f16(af0, bf, acc[0][c], 0, 0, 0);
      acc[1][c] = __builtin_amdgcn_mfma_f32_16x16x32_f16(af1, bf, acc[1][c], 0, 0, 0);
    }
  };

  gloadA(0, a0A, a1A);
  gloadB(0);
  swriteA(0, a0A, a1A);
  swriteB(0);
  gloadA(32, a0B, a1B);
  barrier_lgkm();

  for (int ks = 0; ks < 96; ks += 2) {
    // step ks (buf 0)
    if (ks + 2 < 96) gloadA((ks + 2) * 32, a0A, a1A);
    gloadB((ks + 1) * 32);                 // ks+1 <= 95 always
    compute(0);
    swriteA(1, a0B, a1B);                  // step ks+1 data
    swriteB(1);
    barrier_lgkm();
    // step ks+1 (buf 1)
    if (ks + 3 < 96) { gloadA((ks + 3) * 32, a0B, a1B); }
    if (ks + 2 < 96) { gloadB((ks + 2) * 32); }
    compute(1);
    if (ks + 2 < 96) { swriteA(0, a0A, a1A); swriteB(0); }
    barrier_lgkm();
  }

  // |d|^2: reduce over 4 k-quarter threads of each row
  sq += __shfl_xor(sq, 1);
  sq += __shfl_xor(sq, 2);
  if ((lane & 3) == 0) dn_s[arow] = sq;
  __syncthreads();

  const float sg  = sigma[0];
  const float inv = 0.5f / (sg * sg);
  float dn[2][4];
  bool ok[2][4];
#pragma unroll
  for (int i = 0; i < 2; ++i)
#pragma unroll
    for (int r = 0; r < 4; ++r) {
      int rl = wr * 32 + i * 16 + kg * 4 + r;
      dn[i][r] = dn_s[rl];
      ok[i][r] = (n0 + rl) < NDATA;
    }

  // pass 1: block-local column max
  float pm[8];
#pragma unroll
  for (int c = 0; c < 8; ++c) pm[c] = -1e30f;
#pragma unroll
  for (int i = 0; i < 2; ++i)
#pragma unroll
    for (int r = 0; r < 4; ++r)
#pragma unroll
      for (int c = 0; c < 8; ++c) {
        float v = ok[i][r] ? (2.f * acc[i][c][r] - dn[i][r]) * inv : -1e30f;
        pm[c] = fmaxf(pm[c], v);
      }
#pragma unroll
  for (int c = 0; c < 8; ++c) {
    pm[c] = fmaxf(pm[c], __shfl_xor(pm[c], 16));
    pm[c] = fmaxf(pm[c], __shfl_xor(pm[c], 32));
  }
  if (kg == 0) {
#pragma unroll
    for (int c = 0; c < 8; ++c) m4[wr * 256 + wb * 128 + c * 16 + l15] = pm[c];
  }
  __syncthreads();
  if (tid < 256)
    m_s[tid] = fmaxf(fmaxf(m4[tid], m4[256 + tid]), fmaxf(m4[512 + tid], m4[768 + tid]));
  __syncthreads();

  float mcol[8];
#pragma unroll
  for (int c = 0; c < 8; ++c) mcol[c] = m_s[wb * 128 + c * 16 + l15];

  // pass 2: two 64-n chunks through the trans buffer
  float pl[8] = {};
#pragma unroll
  for (int h = 0; h < 2; ++h) {
    if ((wr >> 1) == h) {
#pragma unroll
      for (int i = 0; i < 2; ++i)
#pragma unroll
        for (int r = 0; r < 4; ++r) {
          const int rl2 = (wr & 1) * 32 + i * 16 + kg * 4 + r;
#pragma unroll
          for (int c = 0; c < 8; ++c) {
            float v = (2.f * acc[i][c][r] - dn[i][r]) * inv;
            float w = ok[i][r] ? __expf(v - mcol[c]) : 0.f;
            pl[c] += w;
            trans[(wb * 128 + c * 16 + l15) * 72 + rl2] = (f16)w;
          }
        }
    }
    __syncthreads();
    {
      const int col = tid >> 1, q = tid & 1;
      const f16* src = trans + col * 72 + q * 32;
      f16* dst = W + (size_t)col * NW + n0 + h * 64 + q * 32;
#pragma unroll
      for (int j = 0; j < 4; ++j)
        *(f16x8*)(dst + j * 8) = *(const f16x8*)(src + j * 8);
    }
    __syncthreads();
  }

#pragma unroll
  for (int c = 0; c < 8; ++c) {
    pl[c] += __shfl_xor(pl[c], 16);
    pl[c] += __shfl_xor(pl[c], 32);
  }
  if (kg == 0) {
#pragma unroll
    for (int c = 0; c < 8; ++c) l4[wr * 256 + wb * 128 + c * 16 + l15] = pl[c];
  }
  __syncthreads();
  if (tid < 256) {
    Mp[blockIdx.x * 256 + tid] = m_s[tid];
    Lp[blockIdx.x * 256 + tid] = l4[tid] + l4[256 + tid] + l4[512 + tid] + l4[768 + tid];
  }
}

// ---------------- K3: combine partials -> M[b], L[b]; then E[g][b] = exp(Mp-M) ----------------
__global__ void k_comb(const float* __restrict__ Mp, const float* __restrict__ Lp,
                       float* __restrict__ M, float* __restrict__ L,
                       f16* __restrict__ E, int ngrp) {
  __shared__ float ms[4][256], ls[4][256];
  __shared__ float mfin[256];
  const int tid = threadIdx.x;
  const int q = tid >> 8, b = tid & 255;
  float m = -1e38f, l = 0.f;
  for (int g = q; g < ngrp; g += 4) {
    float m2 = Mp[g * 256 + b], l2 = Lp[g * 256 + b];
    if (m2 > m) { l = l * __expf(m - m2) + l2; m = m2; }
    else        { l += l2 * __expf(m2 - m); }
  }
  ms[q][b] = m; ls[q][b] = l;
  __syncthreads();
  if (q == 0) {
#pragma unroll
    for (int j = 1; j < 4; ++j) {
      float m2 = ms[j][b], l2 = ls[j][b];
      if (m2 > m) { l = l * __expf(m - m2) + l2; m = m2; }
      else        { l += l2 * __expf(m2 - m); }
    }
    M[b] = m; L[b] = l; mfin[b] = m;
  }
  __syncthreads();
  const float mb = mfin[b];
  for (int g = q; g < ngrp; g += 4)
    E[g * 256 + b] = (f16)__expf(Mp[g * 256 + b] - mb);
}

// ---------------- K4: eps partials = (W*E) @ data, split-K over n ----------------
// 512 thr, tile 256b x 128d (wave 32b x 128d, acc[2][8]), K-step 32.
__global__ __launch_bounds__(512, 4) void k_pv(const float* __restrict__ data,
                                               const f16* __restrict__ W,
                                               const f16* __restrict__ E,
                                               float* __restrict__ part,
                                               int chn, int per8) {
  __shared__ f16 T[2][128 * 40];   // [d][n(32)+pad]
  const int tid = threadIdx.x;
  const int wid = tid >> 6, lane = tid & 63;
  const int l15 = lane & 15, kg = lane >> 4;
  const int bid = blockIdx.x;
  const int swz = (bid & 7) * per8 + (bid >> 3);   // XCD-chunked (grid % 8 == 0)
  const int chunk = swz / NDT3;
  const int dt = swz % NDT3;
  const int d0 = dt * 128;
  const int nstart = chunk * chn;
  const int kst = chn >> 5;
  const int nl = tid >> 4, dl = (tid & 15) * 8;    // staging: 32 n-rows x 128 d (exact)

  f32x4 acc[2][8] = {};
  const int b0 = wid * 32 + l15, b1 = b0 + 16;
  const f16* wp0 = W + (size_t)b0 * NW + nstart + kg * 8;
  const f16* wp1 = W + (size_t)b1 * NW + nstart + kg * 8;

  f32x4 gA0, gA1, gB0, gB1;      // two data prefetch sets (even / odd steps)
  f16x8 w0c, w1c, w0n, w1n;
  f16 hAc, hBc, hAn, hBn;

  auto gload = [&](int ks, f32x4& g0, f32x4& g1) {
    int row = nstart + ks * 32 + nl;
    int rc = row < NDATA ? row : NDATA - 1;        // tail rows have W==0
    const float* gp = data + (size_t)rc * DF + d0 + dl;
    g0 = *(const f32x4*)gp;
    g1 = *(const f32x4*)(gp + 4);
  };
  auto wload = [&](int ks, f16x8& w0, f16x8& w1, f16& ha, f16& hb) {
    w0 = *(const f16x8*)(wp0 + ks * 32);
    w1 = *(const f16x8*)(wp1 + ks * 32);
    int gq = (nstart + ks * 32) >> 7;              // 128-row Mp groups (chn % 128 == 0)
    ha = E[gq * 256 + b0];
    hb = E[gq * 256 + b1];
  };
  auto twrite = [&](int buf, f32x4& g0, f32x4& g1) {
#pragma unroll
    for (int j = 0; j < 8; ++j) {
      float v = (j < 4) ? g0[j] : g1[j - 4];
      int d = dl + j;                              // d <= 127: in-bounds (T is 128 rows)
      int pn = nl ^ (((d >> 3) & 3) << 3);         // bank swizzle
      T[buf][d * 40 + pn] = (f16)v;
    }
  };
  auto compute = [&](int buf, f16x8& w0, f16x8& w1, f16 h0, f16 h1) {
    f16x8 a0, a1;
#pragma unroll
    for (int j = 0; j < 8; ++j) { a0[j] = w0[j] * h0; a1[j] = w1[j] * h1; }
#pragma unroll
    for (int c = 0; c < 8; ++c) {
      int d = c * 16 + l15;
      int pb = (kg * 8) ^ (((d >> 3) & 3) << 3);
      f16x8 bf = *(const f16x8*)(&T[buf][d * 40 + pb]);
      acc[0][c] = __builtin_amdgcn_mfma_f32_16x16x32_f16(a0, bf, acc[0][c], 0, 0, 0);
      acc[1][c] = __builtin_amdgcn_mfma_f32_16x16x32_f16(a1, bf, acc[1][c], 0, 0, 0);
    }
  };

  gload(0, gA0, gA1);
  wload(0, w0c, w1c, hAc, hBc);
  twrite(0, gA0, gA1);
  gload(1, gB0, gB1);
  barrier_lgkm();

  for (int ks = 0; ks < kst; ks += 2) {
    if (ks + 2 < kst) gload(ks + 2, gA0, gA1);     // data 2 ahead
    if (ks + 1 < kst) wload(ks + 1, w0n, w1n, hAn, hBn);
    compute(0, w0c, w1c, hAc, hBc);
    if (ks + 1 < kst) twrite(1, gB0, gB1);         // step ks+1 data
    barrier_lgkm();
    if (ks + 1 < kst) {
      if (ks + 3 < kst) gload(ks + 3, gB0, gB1);
      if (ks + 2 < kst) wload(ks + 2, w0c, w1c, hAc, hBc);
      compute(1, w0n, w1n, hAn, hBn);
      if (ks + 2 < kst) twrite(0, gA0, gA1);       // step ks+2 data
      barrier_lgkm();
    }
  }

  float* pp = part + (size_t)chunk * (BP * DF);
#pragma unroll
  for (int i = 0; i < 2; ++i)
#pragma unroll
    for (int c = 0; c < 8; ++c)
#pragma unroll
      for (int r = 0; r < 4; ++r) {
        int b = wid * 32 + i * 16 + kg * 4 + r;
        int d = d0 + c * 16 + l15;
        pp[(size_t)b * DF + d] = acc[i][c][r];
      }
}

// ---------------- K5: out = (x - (sum partials)/L) / sigma ----------------
__global__ void k_final(const float* __restrict__ x, const float* __restrict__ sigma,
                        const float* __restrict__ part, const float* __restrict__ L,
                        float* __restrict__ out, int nch) {
  int i = blockIdx.x * 256 + threadIdx.x;
  int b = (i * 4) / DF;
  f32x4 s = {};
  for (int c = 0; c < nch; ++c) s += ((const f32x4*)(part + (size_t)c * BP * DF))[i];
  f32x4 xv = ((const f32x4*)x)[i];
  float invL = 1.f / L[b];
  float invsg = 1.f / sigma[0];
  f32x4 r;
#pragma unroll
  for (int j = 0; j < 4; ++j) r[j] = (xv[j] - s[j] * invL) * invsg;
  ((f32x4*)out)[i] = r;
}

extern "C" void kernel_launch(void* const* d_in, const int* in_sizes, int n_in,
                              void* d_out, int out_size, void* d_ws, size_t ws_size,
                              hipStream_t stream) {
  const float* x     = (const float*)d_in[0];
  const float* sigma = (const float*)d_in[1];
  const float* data  = (const float*)d_in[2];
  float* out = (float*)d_out;
  char* ws = (char*)d_ws;

  f16*   W  = (f16*)(ws + OFF_W);
  f16*   xh = (f16*)(ws + OFF_XH);
  float* Mp = (float*)(ws + OFF_MP);
  float* Lp = (float*)(ws + OFF_LP);
  float* M  = (float*)(ws + OFF_M);
  float* L  = (float*)(ws + OFF_L);
  f16*   E  = (f16*)(ws + OFF_E);
  float* P  = (float*)(ws + OFF_P);

  // split-K width: 18 x 2816 = 50688 exactly (2816 % 128 == 0 for Mp groups).
  // grid 432 -> max 2 blocks/CU everywhere (nch=22's grid 528 put a 3rd full
  // block on 16 CUs -> ~0.5 block-time tail).
  int nch = 18, chn = 2816;
  if (ws_size < OFF_P + 18 * SLAB) { nch = 16; chn = 3168; }
  if (ws_size < OFF_P + 16 * SLAB) { nch = 8;  chn = 6336; }
  const int grid_pv = NDT3 * nch;                   // 432 / 384 / 192 — all % 8 == 0
  const int per8 = grid_pv / 8;

  k_prep_x<<<768, 256, 0, stream>>>(x, xh);
  k_qk<<<NGRPQ, 512, 0, stream>>>(data, xh, sigma, W, Mp, Lp);
  k_comb<<<1, 1024, 0, stream>>>(Mp, Lp, M, L, E, NGRPQ);
  k_pv<<<grid_pv, 512, 0, stream>>>(data, W, E, P, chn, per8);
  k_final<<<768, 256, 0, stream>>>(x, sigma, P, L, out, nch);
}

// Round 15
// 461.189 us; speedup vs baseline: 1.6927x; 1.0058x over previous
//
#include <hip/hip_runtime.h>

typedef _Float16 f16;
typedef f16 f16x8 __attribute__((ext_vector_type(8)));
typedef float f32x4 __attribute__((ext_vector_type(4)));

static constexpr int NDATA = 50000;
static constexpr int DF    = 3072;
static constexpr int BP    = 256;
static constexpr int NW    = 50688;   // W row stride / padded N (396*128)
static constexpr int NGRPQ = 396;     // k_qk blocks = softmax groups (128 n each)
static constexpr int NDT3  = 24;      // d-tiles of 128 in k_pv

// workspace offsets (bytes)
static constexpr size_t OFF_W  = 0;            // W : 256*50688*2 = 25952256
static constexpr size_t OFF_XH = 25952256;     // xh: 1572864
static constexpr size_t OFF_MP = 27525120;     // Mp: 396*256*4 = 405504
static constexpr size_t OFF_LP = 27930624;     // Lp: 405504
static constexpr size_t OFF_M  = 28336128;     // M : 1024
static constexpr size_t OFF_L  = 28337152;     // L : 1024
static constexpr size_t OFF_E  = 28338176;     // E : 396*256*2 = 202752 (+pad)
static constexpr size_t OFF_P  = 28542976;     // P : nch * 3145728
static constexpr size_t SLAB   = (size_t)BP * DF * 4;

// lgkm-only barrier: LDS ordered, global loads stay IN FLIGHT (no vmcnt drain)
__device__ __forceinline__ void barrier_lgkm() {
  __builtin_amdgcn_sched_barrier(0);
  asm volatile("s_waitcnt lgkmcnt(0)" ::: "memory");
  __builtin_amdgcn_s_barrier();
  __builtin_amdgcn_sched_barrier(0);
}

// ---------------- K1: x -> fp16 ----------------
__global__ void k_prep_x(const float* __restrict__ x, f16* __restrict__ xh) {
  int i = blockIdx.x * 256 + threadIdx.x;
  f32x4 v = ((const f32x4*)x)[i];
  union { f16 f[4]; short4 s; } u;
  u.f[0] = (f16)v[0]; u.f[1] = (f16)v[1]; u.f[2] = (f16)v[2]; u.f[3] = (f16)v[3];
  ((short4*)xh)[i] = u.s;
}

// ---------------- K2: S-tile via MFMA -> block softmax partials + W' ----------------
// tile 128n x 256b, 8 waves (wave 32n x 128b, acc[2][8]), K-step 32.
// 2-phase-lag A (two reg sets) and 1-phase-lag B (single set, consume-then-reload):
// every staged operand is loaded a full phase before its ds_write -> no exposed
// L2/HBM latency at the vmcnt wait. 1 lgkm-barrier per step.
__global__ __launch_bounds__(512, 4) void k_qk(const float* __restrict__ data,
                                               const f16* __restrict__ xh,
                                               const float* __restrict__ sigma,
                                               f16* __restrict__ W,
                                               float* __restrict__ Mp,
                                               float* __restrict__ Lp) {
  __shared__ char smem[61952];
  f16 (*As)[5120]  = (f16(*)[5120])smem;              // 2 x 10240 B : [128][40]
  f16 (*Bs)[10240] = (f16(*)[10240])(smem + 20480);   // 2 x 20480 B : [256][40]
  float* dn_s = (float*)(smem + 61440);               // [128]
  float* m4   = (float*)smem;                         // alias: [4][256]
  float* l4   = (float*)(smem + 4096);                // alias: [4][256]
  float* m_s  = (float*)(smem + 8192);                // alias: [256]
  f16*  trans = (f16*)(smem + 20480);                 // alias: [256][72]

  const int tid = threadIdx.x;
  const int wid = tid >> 6, lane = tid & 63;
  const int l15 = lane & 15, kg = lane >> 4;
  const int wr = wid >> 1, wb = wid & 1;
  const int n0 = blockIdx.x * 128;

  // A staging: row = tid>>2 (128 rows), 8 floats at (tid&3)*8
  const int arow = tid >> 2, ak = (tid & 3) * 8;
  const int ar_g = n0 + arow;
  const float* ap = data + (size_t)(ar_g < NDATA ? ar_g : NDATA - 1) * DF + ak;
  // B staging: row = tid>>1 (256 rows), 16 f16 at (tid&1)*16
  const int brow = tid >> 1, bk = (tid & 1) * 16;
  const f16* bp = xh + (size_t)brow * DF + bk;

  f32x4 acc[2][8] = {};
  float sq = 0.f;
  f32x4 a0A, a1A, a0B, a1B;     // two A prefetch sets (2-phase lag)
  f16x8 rb0, rb1;               // one B prefetch set (1-phase lag)

  auto gloadA = [&](int k0, f32x4& a0, f32x4& a1) {
    a0 = *(const f32x4*)(ap + k0);
    a1 = *(const f32x4*)(ap + k0 + 4);
  };
  auto gloadB = [&](int k0) {
    rb0 = *(const f16x8*)(bp + k0);
    rb1 = *(const f16x8*)(bp + k0 + 8);
  };
  auto swriteA = [&](int buf, f32x4& a0, f32x4& a1) {
    f16x8 h;
#pragma unroll
    for (int j = 0; j < 4; ++j) {
      h[j] = (f16)a0[j];     sq = fmaf(a0[j], a0[j], sq);
      h[4 + j] = (f16)a1[j]; sq = fmaf(a1[j], a1[j], sq);
    }
    *(f16x8*)(&As[buf][arow * 40 + ak]) = h;
  };
  auto swriteB = [&](int buf) {
    *(f16x8*)(&Bs[buf][brow * 40 + bk]) = rb0;
    *(f16x8*)(&Bs[buf][brow * 40 + bk + 8]) = rb1;
  };
  auto compute = [&](int buf) {
    f16x8 af0 = *(const f16x8*)(&As[buf][(wr * 32 + l15) * 40 + kg * 8]);
    f16x8 af1 = *(const f16x8*)(&As[buf][(wr * 32 + 16 + l15) * 40 + kg * 8]);
#pragma unroll
    for (int c = 0; c < 8; ++c) {
      f16x8 bf = *(const f16x8*)(&Bs[buf][(wb * 128 + c * 16 + l15) * 40 + kg * 8]);
      acc[0][c] = __builtin_amdgcn_mfma_f32_16x16x32_f16(af0, bf, acc[0][c], 0, 0, 0);
      acc[1][c] = __builtin_amdgcn_mfma_f32_16x16x32_f16(af1, bf, acc[1][c], 0, 0, 0);
    }
  };

  gloadA(0, a0A, a1A);
  gloadB(0);
  swriteA(0, a0A, a1A);
  swriteB(0);                   // one-time immediate consume of B(0)
  gloadA(32, a0B, a1B);
  gloadB(32);                   // rb <- B(1), a full phase before its swriteB
  barrier_lgkm();

  for (int ks = 0; ks < 96; ks += 2) {
    // phase even: compute step ks (buf 0); stage step ks+1 into buf 1
    if (ks + 2 < 96) gloadA((ks + 2) * 32, a0A, a1A);
    compute(0);
    swriteA(1, a0B, a1B);
    swriteB(1);                              // rb = B(ks+1), loaded last phase
    if (ks + 2 < 96) gloadB((ks + 2) * 32);  // reload AFTER consume (no clobber)
    barrier_lgkm();
    // phase odd: compute step ks+1 (buf 1); stage step ks+2 into buf 0
    if (ks + 3 < 96) gloadA((ks + 3) * 32, a0B, a1B);
    compute(1);
    if (ks + 2 < 96) { swriteA(0, a0A, a1A); swriteB(0); }  // rb = B(ks+2)
    if (ks + 3 < 96) gloadB((ks + 3) * 32);
    barrier_lgkm();
  }

  // |d|^2: reduce over 4 k-quarter threads of each row
  sq += __shfl_xor(sq, 1);
  sq += __shfl_xor(sq, 2);
  if ((lane & 3) == 0) dn_s[arow] = sq;
  __syncthreads();

  const float sg  = sigma[0];
  const float inv = 0.5f / (sg * sg);
  float dn[2][4];
  bool ok[2][4];
#pragma unroll
  for (int i = 0; i < 2; ++i)
#pragma unroll
    for (int r = 0; r < 4; ++r) {
      int rl = wr * 32 + i * 16 + kg * 4 + r;
      dn[i][r] = dn_s[rl];
      ok[i][r] = (n0 + rl) < NDATA;
    }

  // pass 1: block-local column max
  float pm[8];
#pragma unroll
  for (int c = 0; c < 8; ++c) pm[c] = -1e30f;
#pragma unroll
  for (int i = 0; i < 2; ++i)
#pragma unroll
    for (int r = 0; r < 4; ++r)
#pragma unroll
      for (int c = 0; c < 8; ++c) {
        float v = ok[i][r] ? (2.f * acc[i][c][r] - dn[i][r]) * inv : -1e30f;
        pm[c] = fmaxf(pm[c], v);
      }
#pragma unroll
  for (int c = 0; c < 8; ++c) {
    pm[c] = fmaxf(pm[c], __shfl_xor(pm[c], 16));
    pm[c] = fmaxf(pm[c], __shfl_xor(pm[c], 32));
  }
  if (kg == 0) {
#pragma unroll
    for (int c = 0; c < 8; ++c) m4[wr * 256 + wb * 128 + c * 16 + l15] = pm[c];
  }
  __syncthreads();
  if (tid < 256)
    m_s[tid] = fmaxf(fmaxf(m4[tid], m4[256 + tid]), fmaxf(m4[512 + tid], m4[768 + tid]));
  __syncthreads();

  float mcol[8];
#pragma unroll
  for (int c = 0; c < 8; ++c) mcol[c] = m_s[wb * 128 + c * 16 + l15];

  // pass 2: two 64-n chunks through the trans buffer
  float pl[8] = {};
#pragma unroll
  for (int h = 0; h < 2; ++h) {
    if ((wr >> 1) == h) {
#pragma unroll
      for (int i = 0; i < 2; ++i)
#pragma unroll
        for (int r = 0; r < 4; ++r) {
          const int rl2 = (wr & 1) * 32 + i * 16 + kg * 4 + r;
#pragma unroll
          for (int c = 0; c < 8; ++c) {
            float v = (2.f * acc[i][c][r] - dn[i][r]) * inv;
            float w = ok[i][r] ? __expf(v - mcol[c]) : 0.f;
            pl[c] += w;
            trans[(wb * 128 + c * 16 + l15) * 72 + rl2] = (f16)w;
          }
        }
    }
    __syncthreads();
    {
      const int col = tid >> 1, q = tid & 1;
      const f16* src = trans + col * 72 + q * 32;
      f16* dst = W + (size_t)col * NW + n0 + h * 64 + q * 32;
#pragma unroll
      for (int j = 0; j < 4; ++j)
        *(f16x8*)(dst + j * 8) = *(const f16x8*)(src + j * 8);
    }
    __syncthreads();
  }

#pragma unroll
  for (int c = 0; c < 8; ++c) {
    pl[c] += __shfl_xor(pl[c], 16);
    pl[c] += __shfl_xor(pl[c], 32);
  }
  if (kg == 0) {
#pragma unroll
    for (int c = 0; c < 8; ++c) l4[wr * 256 + wb * 128 + c * 16 + l15] = pl[c];
  }
  __syncthreads();
  if (tid < 256) {
    Mp[blockIdx.x * 256 + tid] = m_s[tid];
    Lp[blockIdx.x * 256 + tid] = l4[tid] + l4[256 + tid] + l4[512 + tid] + l4[768 + tid];
  }
}

// ---------------- K3: combine partials -> M[b], L[b]; then E[g][b] = exp(Mp-M) ----------------
__global__ void k_comb(const float* __restrict__ Mp, const float* __restrict__ Lp,
                       float* __restrict__ M, float* __restrict__ L,
                       f16* __restrict__ E, int ngrp) {
  __shared__ float ms[4][256], ls[4][256];
  __shared__ float mfin[256];
  const int tid = threadIdx.x;
  const int q = tid >> 8, b = tid & 255;
  float m = -1e38f, l = 0.f;
  for (int g = q; g < ngrp; g += 4) {
    float m2 = Mp[g * 256 + b], l2 = Lp[g * 256 + b];
    if (m2 > m) { l = l * __expf(m - m2) + l2; m = m2; }
    else        { l += l2 * __expf(m2 - m); }
  }
  ms[q][b] = m; ls[q][b] = l;
  __syncthreads();
  if (q == 0) {
#pragma unroll
    for (int j = 1; j < 4; ++j) {
      float m2 = ms[j][b], l2 = ls[j][b];
      if (m2 > m) { l = l * __expf(m - m2) + l2; m = m2; }
      else        { l += l2 * __expf(m2 - m); }
    }
    M[b] = m; L[b] = l; mfin[b] = m;
  }
  __syncthreads();
  const float mb = mfin[b];
  for (int g = q; g < ngrp; g += 4)
    E[g * 256 + b] = (f16)__expf(Mp[g * 256 + b] - mb);
}

// ---------------- K4: eps partials = (W*E) @ data, split-K over n ----------------
// 512 thr, tile 256b x 128d (wave 32b x 128d, acc[2][8]), K-step 32.
__global__ __launch_bounds__(512, 4) void k_pv(const float* __restrict__ data,
                                               const f16* __restrict__ W,
                                               const f16* __restrict__ E,
                                               float* __restrict__ part,
                                               int chn, int per8) {
  __shared__ f16 T[2][128 * 40];   // [d][n(32)+pad]
  const int tid = threadIdx.x;
  const int wid = tid >> 6, lane = tid & 63;
  const int l15 = lane & 15, kg = lane >> 4;
  const int bid = blockIdx.x;
  const int swz = (bid & 7) * per8 + (bid >> 3);   // XCD-chunked (grid % 8 == 0)
  const int chunk = swz / NDT3;
  const int dt = swz % NDT3;
  const int d0 = dt * 128;
  const int nstart = chunk * chn;
  const int kst = chn >> 5;
  const int nl = tid >> 4, dl = (tid & 15) * 8;    // staging: 32 n-rows x 128 d (exact)

  f32x4 acc[2][8] = {};
  const int b0 = wid * 32 + l15, b1 = b0 + 16;
  const f16* wp0 = W + (size_t)b0 * NW + nstart + kg * 8;
  const f16* wp1 = W + (size_t)b1 * NW + nstart + kg * 8;

  f32x4 gA0, gA1, gB0, gB1;      // two data prefetch sets (even / odd steps)
  f16x8 w0c, w1c, w0n, w1n;
  f16 hAc, hBc, hAn, hBn;

  auto gload = [&](int ks, f32x4& g0, f32x4& g1) {
    int row = nstart + ks * 32 + nl;
    int rc = row < NDATA ? row : NDATA - 1;        // tail rows have W==0
    const float* gp = data + (size_t)rc * DF + d0 + dl;
    g0 = *(const f32x4*)gp;
    g1 = *(const f32x4*)(gp + 4);
  };
  auto wload = [&](int ks, f16x8& w0, f16x8& w1, f16& ha, f16& hb) {
    w0 = *(const f16x8*)(wp0 + ks * 32);
    w1 = *(const f16x8*)(wp1 + ks * 32);
    int gq = (nstart + ks * 32) >> 7;              // 128-row Mp groups (chn % 128 == 0)
    ha = E[gq * 256 + b0];
    hb = E[gq * 256 + b1];
  };
  auto twrite = [&](int buf, f32x4& g0, f32x4& g1) {
#pragma unroll
    for (int j = 0; j < 8; ++j) {
      float v = (j < 4) ? g0[j] : g1[j - 4];
      int d = dl + j;                              // d <= 127: in-bounds (T is 128 rows)
      int pn = nl ^ (((d >> 3) & 3) << 3);         // bank swizzle
      T[buf][d * 40 + pn] = (f16)v;
    }
  };
  auto compute = [&](int buf, f16x8& w0, f16x8& w1, f16 h0, f16 h1) {
    f16x8 a0, a1;
#pragma unroll
    for (int j = 0; j < 8; ++j) { a0[j] = w0[j] * h0; a1[j] = w1[j] * h1; }
#pragma unroll
    for (int c = 0; c < 8; ++c) {
      int d = c * 16 + l15;
      int pb = (kg * 8) ^ (((d >> 3) & 3) << 3);
      f16x8 bf = *(const f16x8*)(&T[buf][d * 40 + pb]);
      acc[0][c] = __builtin_amdgcn_mfma_f32_16x16x32_f16(a0, bf, acc[0][c], 0, 0, 0);
      acc[1][c] = __builtin_amdgcn_mfma_f32_16x16x32_f16(a1, bf, acc[1][c], 0, 0, 0);
    }
  };

  gload(0, gA0, gA1);
  wload(0, w0c, w1c, hAc, hBc);
  twrite(0, gA0, gA1);
  gload(1, gB0, gB1);
  barrier_lgkm();

  for (int ks = 0; ks < kst; ks += 2) {
    if (ks + 2 < kst) gload(ks + 2, gA0, gA1);     // data 2 ahead
    if (ks + 1 < kst) wload(ks + 1, w0n, w1n, hAn, hBn);
    compute(0, w0c, w1c, hAc, hBc);
    if (ks + 1 < kst) twrite(1, gB0, gB1);         // step ks+1 data
    barrier_lgkm();
    if (ks + 1 < kst) {
      if (ks + 3 < kst) gload(ks + 3, gB0, gB1);
      if (ks + 2 < kst) wload(ks + 2, w0c, w1c, hAc, hBc);
      compute(1, w0n, w1n, hAn, hBn);
      if (ks + 2 < kst) twrite(0, gA0, gA1);       // step ks+2 data
      barrier_lgkm();
    }
  }

  float* pp = part + (size_t)chunk * (BP * DF);
#pragma unroll
  for (int i = 0; i < 2; ++i)
#pragma unroll
    for (int c = 0; c < 8; ++c)
#pragma unroll
      for (int r = 0; r < 4; ++r) {
        int b = wid * 32 + i * 16 + kg * 4 + r;
        int d = d0 + c * 16 + l15;
        pp[(size_t)b * DF + d] = acc[i][c][r];
      }
}

// ---------------- K5: out = (x - (sum partials)/L) / sigma ----------------
__global__ void k_final(const float* __restrict__ x, const float* __restrict__ sigma,
                        const float* __restrict__ part, const float* __restrict__ L,
                        float* __restrict__ out, int nch) {
  int i = blockIdx.x * 256 + threadIdx.x;
  int b = (i * 4) / DF;
  f32x4 s = {};
  for (int c = 0; c < nch; ++c) s += ((const f32x4*)(part + (size_t)c * BP * DF))[i];
  f32x4 xv = ((const f32x4*)x)[i];
  float invL = 1.f / L[b];
  float invsg = 1.f / sigma[0];
  f32x4 r;
#pragma unroll
  for (int j = 0; j < 4; ++j) r[j] = (xv[j] - s[j] * invL) * invsg;
  ((f32x4*)out)[i] = r;
}

extern "C" void kernel_launch(void* const* d_in, const int* in_sizes, int n_in,
                              void* d_out, int out_size, void* d_ws, size_t ws_size,
                              hipStream_t stream) {
  const float* x     = (const float*)d_in[0];
  const float* sigma = (const float*)d_in[1];
  const float* data  = (const float*)d_in[2];
  float* out = (float*)d_out;
  char* ws = (char*)d_ws;

  f16*   W  = (f16*)(ws + OFF_W);
  f16*   xh = (f16*)(ws + OFF_XH);
  float* Mp = (float*)(ws + OFF_MP);
  float* Lp = (float*)(ws + OFF_LP);
  float* M  = (float*)(ws + OFF_M);
  float* L  = (float*)(ws + OFF_L);
  f16*   E  = (f16*)(ws + OFF_E);
  float* P  = (float*)(ws + OFF_P);

  // split-K width: 18 x 2816 = 50688 exactly (2816 % 128 == 0 for Mp groups).
  // grid 432 -> max 2 blocks/CU everywhere.
  int nch = 18, chn = 2816;
  if (ws_size < OFF_P + 18 * SLAB) { nch = 16; chn = 3168; }
  if (ws_size < OFF_P + 16 * SLAB) { nch = 8;  chn = 6336; }
  const int grid_pv = NDT3 * nch;                   // 432 / 384 / 192 — all % 8 == 0
  const int per8 = grid_pv / 8;

  k_prep_x<<<768, 256, 0, stream>>>(x, xh);
  k_qk<<<NGRPQ, 512, 0, stream>>>(data, xh, sigma, W, Mp, Lp);
  k_comb<<<1, 1024, 0, stream>>>(Mp, Lp, M, L, E, NGRPQ);
  k_pv<<<grid_pv, 512, 0, stream>>>(data, W, E, P, chn, per8);
  k_final<<<768, 256, 0, stream>>>(x, sigma, P, L, out, nch);
}

// Round 16
// 451.457 us; speedup vs baseline: 1.7292x; 1.0216x over previous
//
#include <hip/hip_runtime.h>

typedef _Float16 f16;
typedef f16 f16x8 __attribute__((ext_vector_type(8)));
typedef float f32x4 __attribute__((ext_vector_type(4)));

static constexpr int NDATA = 50000;
static constexpr int DF    = 3072;
static constexpr int BP    = 256;
static constexpr int NW    = 50688;   // W row stride / padded N (396*128)
static constexpr int NGRPQ = 396;     // k_qk blocks = softmax groups (128 n each)
static constexpr int NDT3  = 24;      // d-tiles of 128 in k_pv

// workspace offsets (bytes)
static constexpr size_t OFF_W  = 0;            // W : 256*50688*2 = 25952256
static constexpr size_t OFF_XH = 25952256;     // xh: 1572864
static constexpr size_t OFF_MP = 27525120;     // Mp: 396*256*4 = 405504
static constexpr size_t OFF_LP = 27930624;     // Lp: 405504
static constexpr size_t OFF_M  = 28336128;     // M : 1024
static constexpr size_t OFF_L  = 28337152;     // L : 1024
static constexpr size_t OFF_E  = 28338176;     // E : 396*256*2 = 202752 (+pad)
static constexpr size_t OFF_P  = 28542976;     // P : nch * 3145728
static constexpr size_t SLAB   = (size_t)BP * DF * 4;

// lgkm-only barrier: LDS ordered, global loads stay IN FLIGHT (no vmcnt drain)
__device__ __forceinline__ void barrier_lgkm() {
  __builtin_amdgcn_sched_barrier(0);
  asm volatile("s_waitcnt lgkmcnt(0)" ::: "memory");
  __builtin_amdgcn_s_barrier();
  __builtin_amdgcn_sched_barrier(0);
}

// ---------------- K1: x -> fp16 ----------------
__global__ void k_prep_x(const float* __restrict__ x, f16* __restrict__ xh) {
  int i = blockIdx.x * 256 + threadIdx.x;
  f32x4 v = ((const f32x4*)x)[i];
  union { f16 f[4]; short4 s; } u;
  u.f[0] = (f16)v[0]; u.f[1] = (f16)v[1]; u.f[2] = (f16)v[2]; u.f[3] = (f16)v[3];
  ((short4*)xh)[i] = u.s;
}

// ---------------- K2: S-tile via MFMA -> block softmax partials + W' ----------------
// tile 128n x 256b, 8 waves (wave 32n x 128b, acc[2][8]), K-step 32.
// 2-phase-lag A (two reg sets) and 1-phase-lag B (consume-then-reload).
// setprio(1) around the MFMA cluster (T5: 2 blocks/CU at different phases).
__global__ __launch_bounds__(512, 4) void k_qk(const float* __restrict__ data,
                                               const f16* __restrict__ xh,
                                               const float* __restrict__ sigma,
                                               f16* __restrict__ W,
                                               float* __restrict__ Mp,
                                               float* __restrict__ Lp) {
  __shared__ char smem[61952];
  f16 (*As)[5120]  = (f16(*)[5120])smem;              // 2 x 10240 B : [128][40]
  f16 (*Bs)[10240] = (f16(*)[10240])(smem + 20480);   // 2 x 20480 B : [256][40]
  float* dn_s = (float*)(smem + 61440);               // [128]
  float* m4   = (float*)smem;                         // alias: [4][256]
  float* l4   = (float*)(smem + 4096);                // alias: [4][256]
  float* m_s  = (float*)(smem + 8192);                // alias: [256]
  f16*  trans = (f16*)(smem + 20480);                 // alias: [256][72]

  const int tid = threadIdx.x;
  const int wid = tid >> 6, lane = tid & 63;
  const int l15 = lane & 15, kg = lane >> 4;
  const int wr = wid >> 1, wb = wid & 1;
  const int n0 = blockIdx.x * 128;

  // A staging: row = tid>>2 (128 rows), 8 floats at (tid&3)*8
  const int arow = tid >> 2, ak = (tid & 3) * 8;
  const int ar_g = n0 + arow;
  const float* ap = data + (size_t)(ar_g < NDATA ? ar_g : NDATA - 1) * DF + ak;
  // B staging: row = tid>>1 (256 rows), 16 f16 at (tid&1)*16
  const int brow = tid >> 1, bk = (tid & 1) * 16;
  const f16* bp = xh + (size_t)brow * DF + bk;

  f32x4 acc[2][8] = {};
  float sq = 0.f;
  f32x4 a0A, a1A, a0B, a1B;     // two A prefetch sets (2-phase lag)
  f16x8 rb0, rb1;               // one B prefetch set (1-phase lag)

  auto gloadA = [&](int k0, f32x4& a0, f32x4& a1) {
    a0 = *(const f32x4*)(ap + k0);
    a1 = *(const f32x4*)(ap + k0 + 4);
  };
  auto gloadB = [&](int k0) {
    rb0 = *(const f16x8*)(bp + k0);
    rb1 = *(const f16x8*)(bp + k0 + 8);
  };
  auto swriteA = [&](int buf, f32x4& a0, f32x4& a1) {
    f16x8 h;
#pragma unroll
    for (int j = 0; j < 4; ++j) {
      h[j] = (f16)a0[j];     sq = fmaf(a0[j], a0[j], sq);
      h[4 + j] = (f16)a1[j]; sq = fmaf(a1[j], a1[j], sq);
    }
    *(f16x8*)(&As[buf][arow * 40 + ak]) = h;
  };
  auto swriteB = [&](int buf) {
    *(f16x8*)(&Bs[buf][brow * 40 + bk]) = rb0;
    *(f16x8*)(&Bs[buf][brow * 40 + bk + 8]) = rb1;
  };
  auto compute = [&](int buf) {
    f16x8 af0 = *(const f16x8*)(&As[buf][(wr * 32 + l15) * 40 + kg * 8]);
    f16x8 af1 = *(const f16x8*)(&As[buf][(wr * 32 + 16 + l15) * 40 + kg * 8]);
    __builtin_amdgcn_s_setprio(1);
#pragma unroll
    for (int c = 0; c < 8; ++c) {
      f16x8 bf = *(const f16x8*)(&Bs[buf][(wb * 128 + c * 16 + l15) * 40 + kg * 8]);
      acc[0][c] = __builtin_amdgcn_mfma_f32_16x16x32_f16(af0, bf, acc[0][c], 0, 0, 0);
      acc[1][c] = __builtin_amdgcn_mfma_f32_16x16x32_f16(af1, bf, acc[1][c], 0, 0, 0);
    }
    __builtin_amdgcn_s_setprio(0);
  };

  gloadA(0, a0A, a1A);
  gloadB(0);
  swriteA(0, a0A, a1A);
  swriteB(0);                   // one-time immediate consume of B(0)
  gloadA(32, a0B, a1B);
  gloadB(32);                   // rb <- B(1), a full phase before its swriteB
  barrier_lgkm();

  for (int ks = 0; ks < 96; ks += 2) {
    // phase even: compute step ks (buf 0); stage step ks+1 into buf 1
    if (ks + 2 < 96) gloadA((ks + 2) * 32, a0A, a1A);
    compute(0);
    swriteA(1, a0B, a1B);
    swriteB(1);                              // rb = B(ks+1), loaded last phase
    if (ks + 2 < 96) gloadB((ks + 2) * 32);  // reload AFTER consume (no clobber)
    barrier_lgkm();
    // phase odd: compute step ks+1 (buf 1); stage step ks+2 into buf 0
    if (ks + 3 < 96) gloadA((ks + 3) * 32, a0B, a1B);
    compute(1);
    if (ks + 2 < 96) { swriteA(0, a0A, a1A); swriteB(0); }  // rb = B(ks+2)
    if (ks + 3 < 96) gloadB((ks + 3) * 32);
    barrier_lgkm();
  }

  // |d|^2: reduce over 4 k-quarter threads of each row
  sq += __shfl_xor(sq, 1);
  sq += __shfl_xor(sq, 2);
  if ((lane & 3) == 0) dn_s[arow] = sq;
  __syncthreads();

  const float sg  = sigma[0];
  const float inv = 0.5f / (sg * sg);
  float dn[2][4];
  bool ok[2][4];
#pragma unroll
  for (int i = 0; i < 2; ++i)
#pragma unroll
    for (int r = 0; r < 4; ++r) {
      int rl = wr * 32 + i * 16 + kg * 4 + r;
      dn[i][r] = dn_s[rl];
      ok[i][r] = (n0 + rl) < NDATA;
    }

  // pass 1: block-local column max
  float pm[8];
#pragma unroll
  for (int c = 0; c < 8; ++c) pm[c] = -1e30f;
#pragma unroll
  for (int i = 0; i < 2; ++i)
#pragma unroll
    for (int r = 0; r < 4; ++r)
#pragma unroll
      for (int c = 0; c < 8; ++c) {
        float v = ok[i][r] ? (2.f * acc[i][c][r] - dn[i][r]) * inv : -1e30f;
        pm[c] = fmaxf(pm[c], v);
      }
#pragma unroll
  for (int c = 0; c < 8; ++c) {
    pm[c] = fmaxf(pm[c], __shfl_xor(pm[c], 16));
    pm[c] = fmaxf(pm[c], __shfl_xor(pm[c], 32));
  }
  if (kg == 0) {
#pragma unroll
    for (int c = 0; c < 8; ++c) m4[wr * 256 + wb * 128 + c * 16 + l15] = pm[c];
  }
  __syncthreads();
  if (tid < 256)
    m_s[tid] = fmaxf(fmaxf(m4[tid], m4[256 + tid]), fmaxf(m4[512 + tid], m4[768 + tid]));
  __syncthreads();

  float mcol[8];
#pragma unroll
  for (int c = 0; c < 8; ++c) mcol[c] = m_s[wb * 128 + c * 16 + l15];

  // pass 2: two 64-n chunks through the trans buffer
  float pl[8] = {};
#pragma unroll
  for (int h = 0; h < 2; ++h) {
    if ((wr >> 1) == h) {
#pragma unroll
      for (int i = 0; i < 2; ++i)
#pragma unroll
        for (int r = 0; r < 4; ++r) {
          const int rl2 = (wr & 1) * 32 + i * 16 + kg * 4 + r;
#pragma unroll
          for (int c = 0; c < 8; ++c) {
            float v = (2.f * acc[i][c][r] - dn[i][r]) * inv;
            float w = ok[i][r] ? __expf(v - mcol[c]) : 0.f;
            pl[c] += w;
            trans[(wb * 128 + c * 16 + l15) * 72 + rl2] = (f16)w;
          }
        }
    }
    __syncthreads();
    {
      const int col = tid >> 1, q = tid & 1;
      const f16* src = trans + col * 72 + q * 32;
      f16* dst = W + (size_t)col * NW + n0 + h * 64 + q * 32;
#pragma unroll
      for (int j = 0; j < 4; ++j)
        *(f16x8*)(dst + j * 8) = *(const f16x8*)(src + j * 8);
    }
    __syncthreads();
  }

#pragma unroll
  for (int c = 0; c < 8; ++c) {
    pl[c] += __shfl_xor(pl[c], 16);
    pl[c] += __shfl_xor(pl[c], 32);
  }
  if (kg == 0) {
#pragma unroll
    for (int c = 0; c < 8; ++c) l4[wr * 256 + wb * 128 + c * 16 + l15] = pl[c];
  }
  __syncthreads();
  if (tid < 256) {
    Mp[blockIdx.x * 256 + tid] = m_s[tid];
    Lp[blockIdx.x * 256 + tid] = l4[tid] + l4[256 + tid] + l4[512 + tid] + l4[768 + tid];
  }
}

// ---------------- K3: combine partials -> M[b], L[b]; then E[g][b] = exp(Mp-M) ----------------
__global__ void k_comb(const float* __restrict__ Mp, const float* __restrict__ Lp,
                       float* __restrict__ M, float* __restrict__ L,
                       f16* __restrict__ E, int ngrp) {
  __shared__ float ms[4][256], ls[4][256];
  __shared__ float mfin[256];
  const int tid = threadIdx.x;
  const int q = tid >> 8, b = tid & 255;
  float m = -1e38f, l = 0.f;
  for (int g = q; g < ngrp; g += 4) {
    float m2 = Mp[g * 256 + b], l2 = Lp[g * 256 + b];
    if (m2 > m) { l = l * __expf(m - m2) + l2; m = m2; }
    else        { l += l2 * __expf(m2 - m); }
  }
  ms[q][b] = m; ls[q][b] = l;
  __syncthreads();
  if (q == 0) {
#pragma unroll
    for (int j = 1; j < 4; ++j) {
      float m2 = ms[j][b], l2 = ls[j][b];
      if (m2 > m) { l = l * __expf(m - m2) + l2; m = m2; }
      else        { l += l2 * __expf(m2 - m); }
    }
    M[b] = m; L[b] = l; mfin[b] = m;
  }
  __syncthreads();
  const float mb = mfin[b];
  for (int g = q; g < ngrp; g += 4)
    E[g * 256 + b] = (f16)__expf(Mp[g * 256 + b] - mb);
}

// ---------------- K4: eps partials = (W*E) @ data, split-K over n ----------------
// 512 thr, tile 256b x 128d (wave 32b x 128d, acc[2][8]), K-step 32.
// Pair-packed staging: thread covers 2 n-rows x 4 d as uint32 (4 ds_write_b32
// instead of 8 ds_write_b16). setprio around the MFMA cluster.
__global__ __launch_bounds__(512, 4) void k_pv(const float* __restrict__ data,
                                               const f16* __restrict__ W,
                                               const f16* __restrict__ E,
                                               float* __restrict__ part,
                                               int chn, int per8) {
  __shared__ uint32_t T[2][128 * 20];   // [d][n-pair(16)+pad4] packed f16 pairs
  const int tid = threadIdx.x;
  const int wid = tid >> 6, lane = tid & 63;
  const int l15 = lane & 15, kg = lane >> 4;
  const int bid = blockIdx.x;
  const int swz = (bid & 7) * per8 + (bid >> 3);   // XCD-chunked (grid % 8 == 0)
  const int chunk = swz / NDT3;
  const int dt = swz % NDT3;
  const int d0 = dt * 128;
  const int nstart = chunk * chn;
  const int kst = chn >> 5;
  const int np = tid >> 5;            // n-pair 0..15
  const int d4 = (tid & 31) * 4;      // d 0..124 step 4

  f32x4 acc[2][8] = {};
  const int b0 = wid * 32 + l15, b1 = b0 + 16;
  const f16* wp0 = W + (size_t)b0 * NW + nstart + kg * 8;
  const f16* wp1 = W + (size_t)b1 * NW + nstart + kg * 8;

  f32x4 gaA, gbA, gaB, gbB;      // two data prefetch sets (even / odd steps)
  f16x8 w0c, w1c, w0n, w1n;
  f16 hAc, hBc, hAn, hBn;

  auto gload = [&](int ks, f32x4& ga, f32x4& gb) {
    int n = nstart + ks * 32 + np * 2;
    int na = n < NDATA ? n : NDATA - 1;            // tail rows have W==0
    int nb = (n + 1) < NDATA ? (n + 1) : NDATA - 1;
    ga = *(const f32x4*)(data + (size_t)na * DF + d0 + d4);
    gb = *(const f32x4*)(data + (size_t)nb * DF + d0 + d4);
  };
  auto wload = [&](int ks, f16x8& w0, f16x8& w1, f16& ha, f16& hb) {
    w0 = *(const f16x8*)(wp0 + ks * 32);
    w1 = *(const f16x8*)(wp1 + ks * 32);
    int gq = (nstart + ks * 32) >> 7;              // 128-row Mp groups (chn % 128 == 0)
    ha = E[gq * 256 + b0];
    hb = E[gq * 256 + b1];
  };
  auto twrite = [&](int buf, f32x4& ga, f32x4& gb) {
#pragma unroll
    for (int j = 0; j < 4; ++j) {
      int d = d4 + j;                              // d <= 127: in-bounds
      int pn = np ^ (((d >> 3) & 3) << 2);         // pair-unit bank swizzle
      union { f16 f[2]; uint32_t u; } u;
      u.f[0] = (f16)ga[j]; u.f[1] = (f16)gb[j];    // n=2np, 2np+1 at this d
      T[buf][d * 20 + pn] = u.u;
    }
  };
  auto compute = [&](int buf, f16x8& w0, f16x8& w1, f16 h0, f16 h1) {
    f16x8 a0, a1;
#pragma unroll
    for (int j = 0; j < 8; ++j) { a0[j] = w0[j] * h0; a1[j] = w1[j] * h1; }
    __builtin_amdgcn_s_setprio(1);
#pragma unroll
    for (int c = 0; c < 8; ++c) {
      int d = c * 16 + l15;
      int dw = d * 20 + ((kg * 4) ^ (((d >> 3) & 3) << 2));
      f16x8 bf = *(const f16x8*)(&T[buf][dw]);     // 4 consecutive pairs = 8 n
      acc[0][c] = __builtin_amdgcn_mfma_f32_16x16x32_f16(a0, bf, acc[0][c], 0, 0, 0);
      acc[1][c] = __builtin_amdgcn_mfma_f32_16x16x32_f16(a1, bf, acc[1][c], 0, 0, 0);
    }
    __builtin_amdgcn_s_setprio(0);
  };

  gload(0, gaA, gbA);
  wload(0, w0c, w1c, hAc, hBc);
  twrite(0, gaA, gbA);
  gload(1, gaB, gbB);
  barrier_lgkm();

  for (int ks = 0; ks < kst; ks += 2) {
    if (ks + 2 < kst) gload(ks + 2, gaA, gbA);     // data 2 ahead
    if (ks + 1 < kst) wload(ks + 1, w0n, w1n, hAn, hBn);
    compute(0, w0c, w1c, hAc, hBc);
    if (ks + 1 < kst) twrite(1, gaB, gbB);         // step ks+1 data
    barrier_lgkm();
    if (ks + 1 < kst) {
      if (ks + 3 < kst) gload(ks + 3, gaB, gbB);
      if (ks + 2 < kst) wload(ks + 2, w0c, w1c, hAc, hBc);
      compute(1, w0n, w1n, hAn, hBn);
      if (ks + 2 < kst) twrite(0, gaA, gbA);       // step ks+2 data
      barrier_lgkm();
    }
  }

  float* pp = part + (size_t)chunk * (BP * DF);
#pragma unroll
  for (int i = 0; i < 2; ++i)
#pragma unroll
    for (int c = 0; c < 8; ++c)
#pragma unroll
      for (int r = 0; r < 4; ++r) {
        int b = wid * 32 + i * 16 + kg * 4 + r;
        int d = d0 + c * 16 + l15;
        pp[(size_t)b * DF + d] = acc[i][c][r];
      }
}

// ---------------- K5: out = (x - (sum partials)/L) / sigma ----------------
__global__ void k_final(const float* __restrict__ x, const float* __restrict__ sigma,
                        const float* __restrict__ part, const float* __restrict__ L,
                        float* __restrict__ out, int nch) {
  int i = blockIdx.x * 256 + threadIdx.x;
  int b = (i * 4) / DF;
  f32x4 s = {};
  for (int c = 0; c < nch; ++c) s += ((const f32x4*)(part + (size_t)c * BP * DF))[i];
  f32x4 xv = ((const f32x4*)x)[i];
  float invL = 1.f / L[b];
  float invsg = 1.f / sigma[0];
  f32x4 r;
#pragma unroll
  for (int j = 0; j < 4; ++j) r[j] = (xv[j] - s[j] * invL) * invsg;
  ((f32x4*)out)[i] = r;
}

extern "C" void kernel_launch(void* const* d_in, const int* in_sizes, int n_in,
                              void* d_out, int out_size, void* d_ws, size_t ws_size,
                              hipStream_t stream) {
  const float* x     = (const float*)d_in[0];
  const float* sigma = (const float*)d_in[1];
  const float* data  = (const float*)d_in[2];
  float* out = (float*)d_out;
  char* ws = (char*)d_ws;

  f16*   W  = (f16*)(ws + OFF_W);
  f16*   xh = (f16*)(ws + OFF_XH);
  float* Mp = (float*)(ws + OFF_MP);
  float* Lp = (float*)(ws + OFF_LP);
  float* M  = (float*)(ws + OFF_M);
  float* L  = (float*)(ws + OFF_L);
  f16*   E  = (f16*)(ws + OFF_E);
  float* P  = (float*)(ws + OFF_P);

  // split-K width: 18 x 2816 = 50688 exactly (2816 % 128 == 0 for Mp groups).
  // grid 432 -> max 2 blocks/CU everywhere.
  int nch = 18, chn = 2816;
  if (ws_size < OFF_P + 18 * SLAB) { nch = 16; chn = 3168; }
  if (ws_size < OFF_P + 16 * SLAB) { nch = 8;  chn = 6336; }
  const int grid_pv = NDT3 * nch;                   // 432 / 384 / 192 — all % 8 == 0
  const int per8 = grid_pv / 8;

  k_prep_x<<<768, 256, 0, stream>>>(x, xh);
  k_qk<<<NGRPQ, 512, 0, stream>>>(data, xh, sigma, W, Mp, Lp);
  k_comb<<<1, 1024, 0, stream>>>(Mp, Lp, M, L, E, NGRPQ);
  k_pv<<<grid_pv, 512, 0, stream>>>(data, W, E, P, chn, per8);
  k_final<<<768, 256, 0, stream>>>(x, sigma, P, L, out, nch);
}

// Round 17
// 451.271 us; speedup vs baseline: 1.7299x; 1.0004x over previous
//
#include <hip/hip_runtime.h>

typedef _Float16 f16;
typedef f16 f16x8 __attribute__((ext_vector_type(8)));
typedef float f32x4 __attribute__((ext_vector_type(4)));

static constexpr int NDATA = 50000;
static constexpr int DF    = 3072;
static constexpr int BP    = 256;
static constexpr int NW    = 50688;   // W row stride / padded N (396*128)
static constexpr int NGRPQ = 396;     // k_qk blocks = softmax groups (128 n each)
static constexpr int NDT3  = 24;      // d-tiles of 128 in k_pv

// workspace offsets (bytes)
static constexpr size_t OFF_W  = 0;            // W : 256*50688*2 = 25952256
static constexpr size_t OFF_XH = 25952256;     // xh: 1572864
static constexpr size_t OFF_MP = 27525120;     // Mp: 396*256*4 = 405504
static constexpr size_t OFF_LP = 27930624;     // Lp: 405504
static constexpr size_t OFF_M  = 28336128;     // M : 1024
static constexpr size_t OFF_L  = 28337152;     // L : 1024
static constexpr size_t OFF_E  = 28338176;     // E : 396*256*2 = 202752 (+pad)
static constexpr size_t OFF_P  = 28542976;     // P : nch * 3145728
static constexpr size_t SLAB   = (size_t)BP * DF * 4;

// lgkm-only barrier: LDS ordered, global loads stay IN FLIGHT (no vmcnt drain)
__device__ __forceinline__ void barrier_lgkm() {
  __builtin_amdgcn_sched_barrier(0);
  asm volatile("s_waitcnt lgkmcnt(0)" ::: "memory");
  __builtin_amdgcn_s_barrier();
  __builtin_amdgcn_sched_barrier(0);
}

// ---------------- K1: x -> fp16 ----------------
__global__ void k_prep_x(const float* __restrict__ x, f16* __restrict__ xh) {
  int i = blockIdx.x * 256 + threadIdx.x;
  f32x4 v = ((const f32x4*)x)[i];
  union { f16 f[4]; short4 s; } u;
  u.f[0] = (f16)v[0]; u.f[1] = (f16)v[1]; u.f[2] = (f16)v[2]; u.f[3] = (f16)v[3];
  ((short4*)xh)[i] = u.s;
}

// ---------------- K2: S-tile via MFMA -> block softmax partials + W' ----------------
// tile 128n x 256b, 8 waves (wave 32n x 128b, acc[2][8]), K-step 32.
// 2-phase-lag A (two reg sets) and 1-phase-lag B (consume-then-reload).
// setprio(1) around the MFMA cluster.
__global__ __launch_bounds__(512, 4) void k_qk(const float* __restrict__ data,
                                               const f16* __restrict__ xh,
                                               const float* __restrict__ sigma,
                                               f16* __restrict__ W,
                                               float* __restrict__ Mp,
                                               float* __restrict__ Lp) {
  __shared__ char smem[61952];
  f16 (*As)[5120]  = (f16(*)[5120])smem;              // 2 x 10240 B : [128][40]
  f16 (*Bs)[10240] = (f16(*)[10240])(smem + 20480);   // 2 x 20480 B : [256][40]
  float* dn_s = (float*)(smem + 61440);               // [128]
  float* m4   = (float*)smem;                         // alias: [4][256]
  float* l4   = (float*)(smem + 4096);                // alias: [4][256]
  float* m_s  = (float*)(smem + 8192);                // alias: [256]
  f16*  trans = (f16*)(smem + 20480);                 // alias: [256][72]

  const int tid = threadIdx.x;
  const int wid = tid >> 6, lane = tid & 63;
  const int l15 = lane & 15, kg = lane >> 4;
  const int wr = wid >> 1, wb = wid & 1;
  const int n0 = blockIdx.x * 128;

  // A staging: row = tid>>2 (128 rows), 8 floats at (tid&3)*8
  const int arow = tid >> 2, ak = (tid & 3) * 8;
  const int ar_g = n0 + arow;
  const float* ap = data + (size_t)(ar_g < NDATA ? ar_g : NDATA - 1) * DF + ak;
  // B staging: row = tid>>1 (256 rows), 16 f16 at (tid&1)*16
  const int brow = tid >> 1, bk = (tid & 1) * 16;
  const f16* bp = xh + (size_t)brow * DF + bk;

  f32x4 acc[2][8] = {};
  float sq = 0.f;
  f32x4 a0A, a1A, a0B, a1B;     // two A prefetch sets (2-phase lag)
  f16x8 rb0, rb1;               // one B prefetch set (1-phase lag)

  auto gloadA = [&](int k0, f32x4& a0, f32x4& a1) {
    a0 = *(const f32x4*)(ap + k0);
    a1 = *(const f32x4*)(ap + k0 + 4);
  };
  auto gloadB = [&](int k0) {
    rb0 = *(const f16x8*)(bp + k0);
    rb1 = *(const f16x8*)(bp + k0 + 8);
  };
  auto swriteA = [&](int buf, f32x4& a0, f32x4& a1) {
    f16x8 h;
#pragma unroll
    for (int j = 0; j < 4; ++j) {
      h[j] = (f16)a0[j];     sq = fmaf(a0[j], a0[j], sq);
      h[4 + j] = (f16)a1[j]; sq = fmaf(a1[j], a1[j], sq);
    }
    *(f16x8*)(&As[buf][arow * 40 + ak]) = h;
  };
  auto swriteB = [&](int buf) {
    *(f16x8*)(&Bs[buf][brow * 40 + bk]) = rb0;
    *(f16x8*)(&Bs[buf][brow * 40 + bk + 8]) = rb1;
  };
  auto compute = [&](int buf) {
    f16x8 af0 = *(const f16x8*)(&As[buf][(wr * 32 + l15) * 40 + kg * 8]);
    f16x8 af1 = *(const f16x8*)(&As[buf][(wr * 32 + 16 + l15) * 40 + kg * 8]);
    __builtin_amdgcn_s_setprio(1);
#pragma unroll
    for (int c = 0; c < 8; ++c) {
      f16x8 bf = *(const f16x8*)(&Bs[buf][(wb * 128 + c * 16 + l15) * 40 + kg * 8]);
      acc[0][c] = __builtin_amdgcn_mfma_f32_16x16x32_f16(af0, bf, acc[0][c], 0, 0, 0);
      acc[1][c] = __builtin_amdgcn_mfma_f32_16x16x32_f16(af1, bf, acc[1][c], 0, 0, 0);
    }
    __builtin_amdgcn_s_setprio(0);
  };

  gloadA(0, a0A, a1A);
  gloadB(0);
  swriteA(0, a0A, a1A);
  swriteB(0);                   // one-time immediate consume of B(0)
  gloadA(32, a0B, a1B);
  gloadB(32);                   // rb <- B(1), a full phase before its swriteB
  barrier_lgkm();

  for (int ks = 0; ks < 96; ks += 2) {
    // phase even: compute step ks (buf 0); stage step ks+1 into buf 1
    if (ks + 2 < 96) gloadA((ks + 2) * 32, a0A, a1A);
    compute(0);
    swriteA(1, a0B, a1B);
    swriteB(1);                              // rb = B(ks+1), loaded last phase
    if (ks + 2 < 96) gloadB((ks + 2) * 32);  // reload AFTER consume (no clobber)
    barrier_lgkm();
    // phase odd: compute step ks+1 (buf 1); stage step ks+2 into buf 0
    if (ks + 3 < 96) gloadA((ks + 3) * 32, a0B, a1B);
    compute(1);
    if (ks + 2 < 96) { swriteA(0, a0A, a1A); swriteB(0); }  // rb = B(ks+2)
    if (ks + 3 < 96) gloadB((ks + 3) * 32);
    barrier_lgkm();
  }

  // |d|^2: reduce over 4 k-quarter threads of each row
  sq += __shfl_xor(sq, 1);
  sq += __shfl_xor(sq, 2);
  if ((lane & 3) == 0) dn_s[arow] = sq;
  __syncthreads();

  const float sg  = sigma[0];
  const float inv = 0.5f / (sg * sg);
  float dn[2][4];
  bool ok[2][4];
#pragma unroll
  for (int i = 0; i < 2; ++i)
#pragma unroll
    for (int r = 0; r < 4; ++r) {
      int rl = wr * 32 + i * 16 + kg * 4 + r;
      dn[i][r] = dn_s[rl];
      ok[i][r] = (n0 + rl) < NDATA;
    }

  // pass 1: block-local column max
  float pm[8];
#pragma unroll
  for (int c = 0; c < 8; ++c) pm[c] = -1e30f;
#pragma unroll
  for (int i = 0; i < 2; ++i)
#pragma unroll
    for (int r = 0; r < 4; ++r)
#pragma unroll
      for (int c = 0; c < 8; ++c) {
        float v = ok[i][r] ? (2.f * acc[i][c][r] - dn[i][r]) * inv : -1e30f;
        pm[c] = fmaxf(pm[c], v);
      }
#pragma unroll
  for (int c = 0; c < 8; ++c) {
    pm[c] = fmaxf(pm[c], __shfl_xor(pm[c], 16));
    pm[c] = fmaxf(pm[c], __shfl_xor(pm[c], 32));
  }
  if (kg == 0) {
#pragma unroll
    for (int c = 0; c < 8; ++c) m4[wr * 256 + wb * 128 + c * 16 + l15] = pm[c];
  }
  __syncthreads();
  if (tid < 256)
    m_s[tid] = fmaxf(fmaxf(m4[tid], m4[256 + tid]), fmaxf(m4[512 + tid], m4[768 + tid]));
  __syncthreads();

  float mcol[8];
#pragma unroll
  for (int c = 0; c < 8; ++c) mcol[c] = m_s[wb * 128 + c * 16 + l15];

  // pass 2: two 64-n chunks through the trans buffer
  float pl[8] = {};
#pragma unroll
  for (int h = 0; h < 2; ++h) {
    if ((wr >> 1) == h) {
#pragma unroll
      for (int i = 0; i < 2; ++i)
#pragma unroll
        for (int r = 0; r < 4; ++r) {
          const int rl2 = (wr & 1) * 32 + i * 16 + kg * 4 + r;
#pragma unroll
          for (int c = 0; c < 8; ++c) {
            float v = (2.f * acc[i][c][r] - dn[i][r]) * inv;
            float w = ok[i][r] ? __expf(v - mcol[c]) : 0.f;
            pl[c] += w;
            trans[(wb * 128 + c * 16 + l15) * 72 + rl2] = (f16)w;
          }
        }
    }
    __syncthreads();
    {
      const int col = tid >> 1, q = tid & 1;
      const f16* src = trans + col * 72 + q * 32;
      f16* dst = W + (size_t)col * NW + n0 + h * 64 + q * 32;
#pragma unroll
      for (int j = 0; j < 4; ++j)
        *(f16x8*)(dst + j * 8) = *(const f16x8*)(src + j * 8);
    }
    __syncthreads();
  }

#pragma unroll
  for (int c = 0; c < 8; ++c) {
    pl[c] += __shfl_xor(pl[c], 16);
    pl[c] += __shfl_xor(pl[c], 32);
  }
  if (kg == 0) {
#pragma unroll
    for (int c = 0; c < 8; ++c) l4[wr * 256 + wb * 128 + c * 16 + l15] = pl[c];
  }
  __syncthreads();
  if (tid < 256) {
    Mp[blockIdx.x * 256 + tid] = m_s[tid];
    Lp[blockIdx.x * 256 + tid] = l4[tid] + l4[256 + tid] + l4[512 + tid] + l4[768 + tid];
  }
}

// ---------------- K3: combine partials -> M[b], L[b]; then E[g][b] = exp(Mp-M) ----------------
__global__ void k_comb(const float* __restrict__ Mp, const float* __restrict__ Lp,
                       float* __restrict__ M, float* __restrict__ L,
                       f16* __restrict__ E, int ngrp) {
  __shared__ float ms[4][256], ls[4][256];
  __shared__ float mfin[256];
  const int tid = threadIdx.x;
  const int q = tid >> 8, b = tid & 255;
  float m = -1e38f, l = 0.f;
  for (int g = q; g < ngrp; g += 4) {
    float m2 = Mp[g * 256 + b], l2 = Lp[g * 256 + b];
    if (m2 > m) { l = l * __expf(m - m2) + l2; m = m2; }
    else        { l += l2 * __expf(m2 - m); }
  }
  ms[q][b] = m; ls[q][b] = l;
  __syncthreads();
  if (q == 0) {
#pragma unroll
    for (int j = 1; j < 4; ++j) {
      float m2 = ms[j][b], l2 = ls[j][b];
      if (m2 > m) { l = l * __expf(m - m2) + l2; m = m2; }
      else        { l += l2 * __expf(m2 - m); }
    }
    M[b] = m; L[b] = l; mfin[b] = m;
  }
  __syncthreads();
  const float mb = mfin[b];
  for (int g = q; g < ngrp; g += 4)
    E[g * 256 + b] = (f16)__expf(Mp[g * 256 + b] - mb);
}

// ---------------- K4: eps partials = (W*E) @ data, split-K over n ----------------
// 512 thr, tile 256b x 128d (wave 32b x 128d, acc[2][8]), K-step 32.
// Pair-packed staging; T rows widened to 36 dwords + 3-bit slot XOR:
// ds_write_b32 conflicts 4-way -> 2-way (free); reads stay 16B-aligned, 1-way.
__global__ __launch_bounds__(512, 4) void k_pv(const float* __restrict__ data,
                                               const f16* __restrict__ W,
                                               const f16* __restrict__ E,
                                               float* __restrict__ part,
                                               int chn, int per8) {
  __shared__ uint32_t T[2][128 * 36];   // [d][n-pair(16) in 36-dw swizzled rows]
  const int tid = threadIdx.x;
  const int wid = tid >> 6, lane = tid & 63;
  const int l15 = lane & 15, kg = lane >> 4;
  const int bid = blockIdx.x;
  const int swz = (bid & 7) * per8 + (bid >> 3);   // XCD-chunked (grid % 8 == 0)
  const int chunk = swz / NDT3;
  const int dt = swz % NDT3;
  const int d0 = dt * 128;
  const int nstart = chunk * chn;
  const int kst = chn >> 5;
  const int np = tid >> 5;            // n-pair 0..15
  const int d4 = (tid & 31) * 4;      // d 0..124 step 4

  f32x4 acc[2][8] = {};
  const int b0 = wid * 32 + l15, b1 = b0 + 16;
  const f16* wp0 = W + (size_t)b0 * NW + nstart + kg * 8;
  const f16* wp1 = W + (size_t)b1 * NW + nstart + kg * 8;

  f32x4 gaA, gbA, gaB, gbB;      // two data prefetch sets (even / odd steps)
  f16x8 w0c, w1c, w0n, w1n;
  f16 hAc, hBc, hAn, hBn;

  auto gload = [&](int ks, f32x4& ga, f32x4& gb) {
    int n = nstart + ks * 32 + np * 2;
    int na = n < NDATA ? n : NDATA - 1;            // tail rows have W==0
    int nb = (n + 1) < NDATA ? (n + 1) : NDATA - 1;
    ga = *(const f32x4*)(data + (size_t)na * DF + d0 + d4);
    gb = *(const f32x4*)(data + (size_t)nb * DF + d0 + d4);
  };
  auto wload = [&](int ks, f16x8& w0, f16x8& w1, f16& ha, f16& hb) {
    w0 = *(const f16x8*)(wp0 + ks * 32);
    w1 = *(const f16x8*)(wp1 + ks * 32);
    int gq = (nstart + ks * 32) >> 7;              // 128-row Mp groups (32-aligned steps
    ha = E[gq * 256 + b0];                         //  never cross a 128 boundary)
    hb = E[gq * 256 + b1];
  };
  auto twrite = [&](int buf, f32x4& ga, f32x4& gb) {
#pragma unroll
    for (int j = 0; j < 4; ++j) {
      int d = d4 + j;                              // d <= 127: in-bounds
      int pn = np ^ (((d >> 3) & 7) << 2);         // 3-bit slot XOR (<=31 < 36)
      union { f16 f[2]; uint32_t u; } u;
      u.f[0] = (f16)ga[j]; u.f[1] = (f16)gb[j];    // n=2np, 2np+1 at this d
      T[buf][d * 36 + pn] = u.u;
    }
  };
  auto compute = [&](int buf, f16x8& w0, f16x8& w1, f16 h0, f16 h1) {
    f16x8 a0, a1;
#pragma unroll
    for (int j = 0; j < 8; ++j) { a0[j] = w0[j] * h0; a1[j] = w1[j] * h1; }
    __builtin_amdgcn_s_setprio(1);
#pragma unroll
    for (int c = 0; c < 8; ++c) {
      int d = c * 16 + l15;
      int dw = d * 36 + ((kg * 4) ^ (((d >> 3) & 7) << 2));  // mult of 4: 16B-aligned
      f16x8 bf = *(const f16x8*)(&T[buf][dw]);     // 4 consecutive pairs = 8 n
      acc[0][c] = __builtin_amdgcn_mfma_f32_16x16x32_f16(a0, bf, acc[0][c], 0, 0, 0);
      acc[1][c] = __builtin_amdgcn_mfma_f32_16x16x32_f16(a1, bf, acc[1][c], 0, 0, 0);
    }
    __builtin_amdgcn_s_setprio(0);
  };

  gload(0, gaA, gbA);
  wload(0, w0c, w1c, hAc, hBc);
  twrite(0, gaA, gbA);
  gload(1, gaB, gbB);
  barrier_lgkm();

  for (int ks = 0; ks < kst; ks += 2) {
    if (ks + 2 < kst) gload(ks + 2, gaA, gbA);     // data 2 ahead
    if (ks + 1 < kst) wload(ks + 1, w0n, w1n, hAn, hBn);
    compute(0, w0c, w1c, hAc, hBc);
    if (ks + 1 < kst) twrite(1, gaB, gbB);         // step ks+1 data
    barrier_lgkm();
    if (ks + 1 < kst) {
      if (ks + 3 < kst) gload(ks + 3, gaB, gbB);
      if (ks + 2 < kst) wload(ks + 2, w0c, w1c, hAc, hBc);
      compute(1, w0n, w1n, hAn, hBn);
      if (ks + 2 < kst) twrite(0, gaA, gbA);       // step ks+2 data
      barrier_lgkm();
    }
  }

  float* pp = part + (size_t)chunk * (BP * DF);
#pragma unroll
  for (int i = 0; i < 2; ++i)
#pragma unroll
    for (int c = 0; c < 8; ++c)
#pragma unroll
      for (int r = 0; r < 4; ++r) {
        int b = wid * 32 + i * 16 + kg * 4 + r;
        int d = d0 + c * 16 + l15;
        pp[(size_t)b * DF + d] = acc[i][c][r];
      }
}

// ---------------- K5: out = (x - (sum partials)/L) / sigma ----------------
__global__ void k_final(const float* __restrict__ x, const float* __restrict__ sigma,
                        const float* __restrict__ part, const float* __restrict__ L,
                        float* __restrict__ out, int nch) {
  int i = blockIdx.x * 256 + threadIdx.x;
  int b = (i * 4) / DF;
  f32x4 s = {};
  for (int c = 0; c < nch; ++c) s += ((const f32x4*)(part + (size_t)c * BP * DF))[i];
  f32x4 xv = ((const f32x4*)x)[i];
  float invL = 1.f / L[b];
  float invsg = 1.f / sigma[0];
  f32x4 r;
#pragma unroll
  for (int j = 0; j < 4; ++j) r[j] = (xv[j] - s[j] * invL) * invsg;
  ((f32x4*)out)[i] = r;
}

extern "C" void kernel_launch(void* const* d_in, const int* in_sizes, int n_in,
                              void* d_out, int out_size, void* d_ws, size_t ws_size,
                              hipStream_t stream) {
  const float* x     = (const float*)d_in[0];
  const float* sigma = (const float*)d_in[1];
  const float* data  = (const float*)d_in[2];
  float* out = (float*)d_out;
  char* ws = (char*)d_ws;

  f16*   W  = (f16*)(ws + OFF_W);
  f16*   xh = (f16*)(ws + OFF_XH);
  float* Mp = (float*)(ws + OFF_MP);
  float* Lp = (float*)(ws + OFF_LP);
  float* M  = (float*)(ws + OFF_M);
  float* L  = (float*)(ws + OFF_L);
  f16*   E  = (f16*)(ws + OFF_E);
  float* P  = (float*)(ws + OFF_P);

  // split-K width: 18 x 2816 = 50688 exactly. grid 432 -> max 2 blocks/CU.
  int nch = 18, chn = 2816;
  if (ws_size < OFF_P + 18 * SLAB) { nch = 16; chn = 3168; }
  if (ws_size < OFF_P + 16 * SLAB) { nch = 8;  chn = 6336; }
  const int grid_pv = NDT3 * nch;                   // 432 / 384 / 192 — all % 8 == 0
  const int per8 = grid_pv / 8;

  k_prep_x<<<768, 256, 0, stream>>>(x, xh);
  k_qk<<<NGRPQ, 512, 0, stream>>>(data, xh, sigma, W, Mp, Lp);
  k_comb<<<1, 1024, 0, stream>>>(Mp, Lp, M, L, E, NGRPQ);
  k_pv<<<grid_pv, 512, 0, stream>>>(data, W, E, P, chn, per8);
  k_final<<<768, 256, 0, stream>>>(x, sigma, P, L, out, nch);
}